// Round 10
// baseline (161.319 us; speedup 1.0000x reference)
//
#include <hip/hip_runtime.h>
#include <hip/hip_bf16.h>

// 3-layer GCN, N=100000, E=1000000, dims 64 -> 64 -> 32 -> 16.
// s1 = x@W1 (bf16); a_k = b_k + segment_sum(w_e * s_k[col], row) (bf16);
// s_{k+1} = lrelu(a_k) @ W_{k+1}; final: out = lrelu(a_3) (f32).
// CSR via two-level LDS bucket counting sort (zero global atomics, R8).
// R10: UNFUSE hist1/gemm1 — R9's fusion co-compiled both bodies into one
// 136-VGPR allocation (occupancy 8.5%, VALUBusy 21% -> 44us for ~10us of
// work). Standalone kernels each get their own register budget. Everything
// else (CHUNK=4096, folded scan2) kept from R9.

__device__ __forceinline__ float lrelu(float v) { return v > 0.0f ? v : 0.25f * v; }
__device__ __forceinline__ float bflo(unsigned u) { return __uint_as_float(u << 16); }
__device__ __forceinline__ float bfhi(unsigned u) { return __uint_as_float(u & 0xffff0000u); }
__device__ __forceinline__ unsigned short f2bf(float f) {          // round-to-nearest-even
    unsigned u = __float_as_uint(f);
    return (unsigned short)((u + 0x7fffu + ((u >> 16) & 1u)) >> 16);
}
__device__ __forceinline__ unsigned packbf(float a, float b) {
    return (unsigned)f2bf(a) | ((unsigned)f2bf(b) << 16);
}

// ---------------- bucket counting-sort CSR build ----------------

constexpr int SCAN_T = 256;
constexpr int SCAN_PER = 8;
constexpr int SCAN_CHUNK = SCAN_T * SCAN_PER;  // 2048 (scan1 granularity; getI >>11)
constexpr int CHUNK = 4096;                    // edges per hist/place1 block
constexpr int BKT_BITS = 7;
constexpr int BKTSZ = 128;                     // nodes per bucket
constexpr int MAXBKT = 1024;                   // LDS bins (N <= 131072)
constexpr int MAXNSC = 128;                    // max scan1 chunks (T <= 262144)

// Build exclusive prefix of bsum[0..nsc-1] into bofs[] (LDS), nsc <= 128.
__device__ __forceinline__ void build_bofs(const int* __restrict__ bsum, int nsc,
                                           int* tmp, int* bofs) {
    int t = threadIdx.x;
    int v = (t < MAXNSC && t < nsc) ? bsum[t] : 0;
    if (t < MAXNSC) tmp[t] = v;
    __syncthreads();
    for (int off = 1; off < MAXNSC; off <<= 1) {
        int add = (t < MAXNSC && t >= off) ? tmp[t - off] : 0;
        __syncthreads();
        if (t < MAXNSC) tmp[t] += add;
        __syncthreads();
    }
    if (t < MAXNSC) bofs[t] = tmp[t] - v;   // exclusive
    __syncthreads();
}

__device__ __forceinline__ int getI(const int* __restrict__ I,
                                    const int* __restrict__ bofs, size_t idx) {
    return I[idx] + bofs[idx >> 11];    // 2048-element scan chunks
}

// hists[bin*NB + blk] = #edges of chunk blk with row>>7 == bin
__global__ void __launch_bounds__(256)
hist1_kernel(const int* __restrict__ row, int* __restrict__ hists,
             int E, int nbkt, int NB) {
    __shared__ int hist[MAXBKT];
    for (int i = threadIdx.x; i < nbkt; i += 256) hist[i] = 0;
    __syncthreads();
    int e0 = blockIdx.x * CHUNK;
    int e1 = min(e0 + CHUNK, E);
    for (int e = e0 + threadIdx.x; e < e1; e += 256)
        atomicAdd(&hist[row[e] >> BKT_BITS], 1);            // LDS atomic
    __syncthreads();
    for (int i = threadIdx.x; i < nbkt; i += 256)
        hists[(size_t)i * NB + blockIdx.x] = hist[i];
}

// per-chunk inclusive scan of the flat hist matrix (T = nbkt*NB elements)
__global__ void __launch_bounds__(SCAN_T)
scan1_kernel(int* __restrict__ I, int* __restrict__ bsum, int T) {
    __shared__ int lds[SCAN_T];
    int t = threadIdx.x;
    int base = blockIdx.x * SCAN_CHUNK + t * SCAN_PER;
    int v[SCAN_PER];
    int run = 0;
#pragma unroll
    for (int j = 0; j < SCAN_PER; ++j) {
        int i = base + j;
        run += (i < T) ? I[i] : 0;
        v[j] = run;
    }
    lds[t] = run;
    __syncthreads();
    for (int off = 1; off < SCAN_T; off <<= 1) {
        int add = (t >= off) ? lds[t - off] : 0;
        __syncthreads();
        lds[t] += add;
        __syncthreads();
    }
    int excl = lds[t] - run;
#pragma unroll
    for (int j = 0; j < SCAN_PER; ++j) {
        int i = base + j;
        if (i < T) I[i] = v[j] + excl;
    }
    if (t == SCAN_T - 1) bsum[blockIdx.x] = lds[t];
}

// place edges into bucket-contiguous eb1; pos = (scanned excl base) + LDS rank.
__global__ void __launch_bounds__(256)
place1_kernel(const int* __restrict__ row, const int* __restrict__ col,
              const float* __restrict__ w, const int* __restrict__ I,
              const int* __restrict__ bsum, int nsc, int2* __restrict__ eb1,
              int E, int nbkt, int NB) {
    __shared__ int srow[CHUNK];
    __shared__ int hist[MAXBKT];
    __shared__ int tmp[MAXNSC];
    __shared__ int bofs[MAXNSC];
    build_bofs(bsum, nsc, tmp, bofs);
    for (int i = threadIdx.x; i < nbkt; i += 256) hist[i] = 0;
    int e0 = blockIdx.x * CHUNK;
    int e1 = min(e0 + CHUNK, E);
    for (int e = e0 + threadIdx.x; e < e1; e += 256) srow[e - e0] = row[e];
    __syncthreads();
    for (int i = threadIdx.x; i < e1 - e0; i += 256)
        atomicAdd(&hist[srow[i] >> BKT_BITS], 1);
    __syncthreads();
    // hist[bin] <- global exclusive base for (bin, thisblock)
    for (int i = threadIdx.x; i < nbkt; i += 256) {
        size_t idx = (size_t)i * NB + blockIdx.x;
        hist[i] = getI(I, bofs, idx) - hist[i];
    }
    __syncthreads();
    for (int e = e0 + threadIdx.x; e < e1; e += 256) {
        int r = srow[e - e0];
        int pos = atomicAdd(&hist[r >> BKT_BITS], 1);        // LDS atomic, returns slot
        eb1[pos] = make_int2(((r & (BKTSZ - 1)) << 20) | col[e], __float_as_int(w[e]));
    }
}

// one block per bucket: exact per-node CSR within the bucket; emits edges[] + rs[].
__global__ void __launch_bounds__(256)
place2_kernel(const int2* __restrict__ eb1, const int* __restrict__ I,
              const int* __restrict__ bsum, int nsc, int2* __restrict__ edges,
              int* __restrict__ rs, int N, int NB) {
    __shared__ int hist[BKTSZ];
    __shared__ int scanv[BKTSZ];
    __shared__ int tmp[MAXNSC];
    __shared__ int bofs[MAXNSC];
    build_bofs(bsum, nsc, tmp, bofs);
    int b = blockIdx.x;
    int t = threadIdx.x;
    int bstart = (b == 0) ? 0 : getI(I, bofs, (size_t)b * NB - 1);
    int bend   = getI(I, bofs, (size_t)(b + 1) * NB - 1);
    if (t < BKTSZ) hist[t] = 0;
    __syncthreads();
    for (int e = bstart + t; e < bend; e += 256)
        atomicAdd(&hist[(eb1[e].x >> 20) & (BKTSZ - 1)], 1);
    __syncthreads();
    int cval = (t < BKTSZ) ? hist[t] : 0;
    if (t < BKTSZ) scanv[t] = cval;
    __syncthreads();
    for (int off = 1; off < BKTSZ; off <<= 1) {
        int add = (t < BKTSZ && t >= off) ? scanv[t - off] : 0;
        __syncthreads();
        if (t < BKTSZ) scanv[t] += add;
        __syncthreads();
    }
    if (t < BKTSZ) {
        int gnode = b * BKTSZ + t;
        if (gnode < N) rs[gnode] = bstart + scanv[t];        // inclusive ends
        hist[t] = bstart + scanv[t] - cval;                  // node base for placing
    }
    __syncthreads();
    for (int e = bstart + t; e < bend; e += 256) {
        int2 ev = eb1[e];
        int lrow = (ev.x >> 20) & (BKTSZ - 1);
        int pos = atomicAdd(&hist[lrow], 1);                 // LDS atomic
        edges[pos] = make_int2(ev.x & 0xFFFFF, ev.y);        // {col, w_bits}
    }
}

// ---------------- dense transform: out = act(in) @ W, bf16 out ----------------
// NPT=4 nodes x 4 cols per thread -> each W ds_read_b128 feeds 16 FMAs.

template <int K, int M, int NPT, bool ACT, bool INBF16>
__global__ void __launch_bounds__(256)
gemm_kernel(const void* __restrict__ inv, const float* __restrict__ W,
            __hip_bfloat16* __restrict__ out, int N) {
    constexpr int QM = M / 4;
    __shared__ float Ws[K * M];
    for (int i = threadIdx.x; i < K * M / 4; i += 256)
        reinterpret_cast<float4*>(Ws)[i] = reinterpret_cast<const float4*>(W)[i];
    __syncthreads();
    int t = blockIdx.x * 256 + threadIdx.x;
    int qc = t & (QM - 1);
    int ngrp = t / QM;
    int nb = ngrp * NPT;
    if (nb >= N) return;

    float acc[NPT][4];
#pragma unroll
    for (int i = 0; i < NPT; ++i) { acc[i][0] = acc[i][1] = acc[i][2] = acc[i][3] = 0.f; }

    const float* inf = (const float*)inv;
    const unsigned short* inb = (const unsigned short*)inv;

#pragma unroll
    for (int k0 = 0; k0 < K; k0 += 4) {
        float4 w0 = *reinterpret_cast<const float4*>(&Ws[(k0 + 0) * M + qc * 4]);
        float4 w1 = *reinterpret_cast<const float4*>(&Ws[(k0 + 1) * M + qc * 4]);
        float4 w2 = *reinterpret_cast<const float4*>(&Ws[(k0 + 2) * M + qc * 4]);
        float4 w3 = *reinterpret_cast<const float4*>(&Ws[(k0 + 3) * M + qc * 4]);
#pragma unroll
        for (int i = 0; i < NPT; ++i) {
            float4 xv;
            if constexpr (INBF16) {
                uint2 u = *reinterpret_cast<const uint2*>(inb + (size_t)(nb + i) * K + k0);
                xv.x = bflo(u.x); xv.y = bfhi(u.x); xv.z = bflo(u.y); xv.w = bfhi(u.y);
            } else {
                xv = *reinterpret_cast<const float4*>(inf + (size_t)(nb + i) * K + k0);
            }
            if (ACT) { xv.x = lrelu(xv.x); xv.y = lrelu(xv.y); xv.z = lrelu(xv.z); xv.w = lrelu(xv.w); }
            acc[i][0] += xv.x * w0.x + xv.y * w1.x + xv.z * w2.x + xv.w * w3.x;
            acc[i][1] += xv.x * w0.y + xv.y * w1.y + xv.z * w2.y + xv.w * w3.y;
            acc[i][2] += xv.x * w0.z + xv.y * w1.z + xv.z * w2.z + xv.w * w3.z;
            acc[i][3] += xv.x * w0.w + xv.y * w1.w + xv.z * w2.w + xv.w * w3.w;
        }
    }
#pragma unroll
    for (int i = 0; i < NPT; ++i) {
        uint2 o;
        o.x = packbf(acc[i][0], acc[i][1]);
        o.y = packbf(acc[i][2], acc[i][3]);
        *reinterpret_cast<uint2*>(out + (size_t)(nb + i) * M + qc * 4) = o;
    }
}

// ---------------- CSR aggregation: wide gathers, G = M/VPT lanes per node ----------------

template <int M, int G, bool ACTOUT, bool OUTBF16>
__global__ void __launch_bounds__(256)
agg_kernel(const int* __restrict__ rs, const int2* __restrict__ edges,
           const __hip_bfloat16* __restrict__ sup, const float* __restrict__ b,
           void* __restrict__ outv, int N) {
    constexpr int VPT = M / G;
    static_assert(VPT == 8 || VPT == 4, "VPT must be 8 or 4");
    int tid = blockIdx.x * blockDim.x + threadIdx.x;
    int node = tid / G;
    if (node >= N) return;
    int g = tid - node * G;

    float acc[VPT];
#pragma unroll
    for (int j = 0; j < VPT; ++j) acc[j] = b[g * VPT + j];

    int beg = node ? rs[node - 1] : 0;
    int end = rs[node];
    const unsigned short* su = reinterpret_cast<const unsigned short*>(sup) + g * VPT;

    for (int j0 = beg; j0 < end; j0 += G) {
        int jl = j0 + g;
        int2 ev = edges[jl < end ? jl : end - 1];   // coalesced; clamped lanes never broadcast
        int cnt = min(G, end - j0);
#pragma unroll 4
        for (int jj = 0; jj < cnt; ++jj) {
            int   col = __shfl(ev.x, jj, G);
            float w   = __int_as_float(__shfl(ev.y, jj, G));
            const unsigned short* p = su + (size_t)col * M;
            if constexpr (VPT == 8) {
                uint4 u = *reinterpret_cast<const uint4*>(p);   // 8 bf16 = 16B/lane
                acc[0] += w * bflo(u.x); acc[1] += w * bfhi(u.x);
                acc[2] += w * bflo(u.y); acc[3] += w * bfhi(u.y);
                acc[4] += w * bflo(u.z); acc[5] += w * bfhi(u.z);
                acc[6] += w * bflo(u.w); acc[7] += w * bfhi(u.w);
            } else {
                uint2 u = *reinterpret_cast<const uint2*>(p);   // 4 bf16 = 8B/lane
                acc[0] += w * bflo(u.x); acc[1] += w * bfhi(u.x);
                acc[2] += w * bflo(u.y); acc[3] += w * bfhi(u.y);
            }
        }
    }
    if (ACTOUT) {
#pragma unroll
        for (int j = 0; j < VPT; ++j) acc[j] = lrelu(acc[j]);
    }
    if constexpr (OUTBF16) {
        __hip_bfloat16* out = (__hip_bfloat16*)outv;
        if constexpr (VPT == 8) {
            uint4 o = { packbf(acc[0], acc[1]), packbf(acc[2], acc[3]),
                        packbf(acc[4], acc[5]), packbf(acc[6], acc[7]) };
            *reinterpret_cast<uint4*>(out + (size_t)node * M + g * 8) = o;
        } else {
            uint2 o = { packbf(acc[0], acc[1]), packbf(acc[2], acc[3]) };
            *reinterpret_cast<uint2*>(out + (size_t)node * M + g * 4) = o;
        }
    } else {
        float* out = (float*)outv;
        if constexpr (VPT == 8) {
            float4 o0 = {acc[0], acc[1], acc[2], acc[3]};
            float4 o1 = {acc[4], acc[5], acc[6], acc[7]};
            reinterpret_cast<float4*>(out + (size_t)node * M + g * 8)[0] = o0;
            reinterpret_cast<float4*>(out + (size_t)node * M + g * 8)[1] = o1;
        } else {
            float4 o = {acc[0], acc[1], acc[2], acc[3]};
            *reinterpret_cast<float4*>(out + (size_t)node * M + g * 4) = o;
        }
    }
}

extern "C" void kernel_launch(void* const* d_in, const int* in_sizes, int n_in,
                              void* d_out, int out_size, void* d_ws, size_t ws_size,
                              hipStream_t stream) {
    const float* x    = (const float*)d_in[0];
    const int*   erow = (const int*)  d_in[1];
    const int*   ecol = (const int*)  d_in[2];
    const float* ew   = (const float*)d_in[3];
    const float* W1   = (const float*)d_in[4];
    const float* b1   = (const float*)d_in[5];
    const float* W2   = (const float*)d_in[6];
    const float* b2   = (const float*)d_in[7];
    const float* W3   = (const float*)d_in[8];
    const float* b3   = (const float*)d_in[9];
    float* out = (float*)d_out;

    const int N = in_sizes[0] / 64;   // 100000
    const int E = in_sizes[1];        // 1000000

    auto cdiv = [](long a, long b) { return (int)((a + b - 1) / b); };
    const int NB   = cdiv(E, CHUNK);          // 245 edge chunks
    const int nbkt = cdiv(N, BKTSZ);          // 782 buckets
    const long T   = (long)nbkt * NB;         // 191,590 flat hist entries
    const int nsc  = cdiv(T, SCAN_CHUNK);     // 94 scan chunks (<= MAXNSC)

    // Workspace:
    //   [0,      12.8MB)  s1 (N*64 bf16); later s3 (N*16 bf16)
    //   [12.8,   25.6MB)  a1 (N*64 bf16); later a2 (N*32 bf16)
    //   [25.6,   32.0MB)  s2 (N*32 bf16)
    //   [32.0MB, ...)     I[T] (0.8MB), bsum[128], rs[N] (0.4MB),
    //                     eb1[E] int2 (8MB), edges[E] int2 (8MB)
    char* wsc = (char*)d_ws;
    const size_t SZ64B = (size_t)N * 64 * 2;   // 12.8 MB
    const size_t SZ32B = (size_t)N * 32 * 2;   // 6.4 MB
    __hip_bfloat16* s1 = (__hip_bfloat16*)(wsc);
    __hip_bfloat16* a1 = (__hip_bfloat16*)(wsc + SZ64B);
    __hip_bfloat16* s2 = (__hip_bfloat16*)(wsc + 2 * SZ64B);
    __hip_bfloat16* a2 = (__hip_bfloat16*)(wsc + SZ64B);          // reuse a1 (dead)
    __hip_bfloat16* s3 = (__hip_bfloat16*)(wsc);                  // reuse s1 (dead)

    char* csr = wsc + 2 * SZ64B + SZ32B;
    int*  I     = (int*)csr;                       // T ints
    int*  bsum  = I + T;                           // MAXNSC ints
    int*  rs    = bsum + MAXNSC;                   // N ints
    int2* eb1   = (int2*)(rs + N);                 // E int2
    int2* edges = eb1 + E;                         // E int2

    const int B = 256;

    // ---- CSR build (no global atomics) ----
    hist1_kernel<<<NB, B, 0, stream>>>(erow, I, E, nbkt, NB);
    scan1_kernel<<<nsc, SCAN_T, 0, stream>>>(I, bsum, (int)T);
    place1_kernel<<<NB, B, 0, stream>>>(erow, ecol, ew, I, bsum, nsc, eb1, E, nbkt, NB);
    place2_kernel<<<nbkt, B, 0, stream>>>(eb1, I, bsum, nsc, edges, rs, N, NB);

    // ---- Layer 1: 64 -> 64 ----
    gemm_kernel<64, 64, 4, false, false><<<cdiv((long)(N / 4) * 16, B), B, 0, stream>>>(x, W1, s1, N);
    agg_kernel<64, 8, false, true><<<cdiv((long)N * 8, B), B, 0, stream>>>(rs, edges, s1, b1, a1, N);

    // ---- Layer 2: 64 -> 32 (lrelu on load) ----
    gemm_kernel<64, 32, 4, true, true><<<cdiv((long)(N / 4) * 8, B), B, 0, stream>>>(a1, W2, s2, N);
    agg_kernel<32, 4, false, true><<<cdiv((long)N * 4, B), B, 0, stream>>>(rs, edges, s2, b2, a2, N);

    // ---- Layer 3: 32 -> 16 (lrelu on load; final lrelu fused into agg) ----
    gemm_kernel<32, 16, 4, true, true><<<cdiv((long)(N / 4) * 4, B), B, 0, stream>>>(a2, W3, s3, N);
    agg_kernel<16, 4, true, false><<<cdiv((long)N * 4, B), B, 0, stream>>>(rs, edges, s3, b3, out, N);
}

// Round 11
// 118.379 us; speedup vs baseline: 1.3627x; 1.3627x over previous
//
#include <hip/hip_runtime.h>
#include <hip/hip_bf16.h>

// 3-layer GCN, N=100000, E=1000000, dims 64 -> 64 -> 32 -> 16.
// s_k = a_{k-1} @ W_k via MFMA (bf16); a_k = lrelu(b_k + segsum(w_e * s_k[col]))
// stored bf16 (f32 for final). CSR via two-level LDS bucket counting sort (R8-R10).
// R11: GEMMs moved to the matrix pipe. R10 showed the scalar gemm compiles to
// 140 VGPR -> 7.9% occupancy -> 40us latency-bound for ~9us of VALU work.
// MFMA 16x16x32 bf16: wave = 16-node x M tile, B-frags loop-invariant from LDS,
// lrelu folded into agg epilogue (0.25x is exponent-exact: lrelu(bf16(v)) ==
// bf16(lrelu(v))), so gemm is a pure GEMM. agg/CSR kernels unchanged.

typedef short bf16x8 __attribute__((ext_vector_type(8)));
typedef float f32x4 __attribute__((ext_vector_type(4)));

__device__ __forceinline__ float lrelu(float v) { return v > 0.0f ? v : 0.25f * v; }
__device__ __forceinline__ float bflo(unsigned u) { return __uint_as_float(u << 16); }
__device__ __forceinline__ float bfhi(unsigned u) { return __uint_as_float(u & 0xffff0000u); }
__device__ __forceinline__ unsigned short f2bf(float f) {          // round-to-nearest-even
    unsigned u = __float_as_uint(f);
    return (unsigned short)((u + 0x7fffu + ((u >> 16) & 1u)) >> 16);
}
__device__ __forceinline__ unsigned packbf(float a, float b) {
    return (unsigned)f2bf(a) | ((unsigned)f2bf(b) << 16);
}

// ---------------- bucket counting-sort CSR build (unchanged from R10) ----------------

constexpr int SCAN_T = 256;
constexpr int SCAN_PER = 8;
constexpr int SCAN_CHUNK = SCAN_T * SCAN_PER;  // 2048 (scan1 granularity; getI >>11)
constexpr int CHUNK = 4096;                    // edges per hist/place1 block
constexpr int BKT_BITS = 7;
constexpr int BKTSZ = 128;                     // nodes per bucket
constexpr int MAXBKT = 1024;                   // LDS bins (N <= 131072)
constexpr int MAXNSC = 128;                    // max scan1 chunks (T <= 262144)

__device__ __forceinline__ void build_bofs(const int* __restrict__ bsum, int nsc,
                                           int* tmp, int* bofs) {
    int t = threadIdx.x;
    int v = (t < MAXNSC && t < nsc) ? bsum[t] : 0;
    if (t < MAXNSC) tmp[t] = v;
    __syncthreads();
    for (int off = 1; off < MAXNSC; off <<= 1) {
        int add = (t < MAXNSC && t >= off) ? tmp[t - off] : 0;
        __syncthreads();
        if (t < MAXNSC) tmp[t] += add;
        __syncthreads();
    }
    if (t < MAXNSC) bofs[t] = tmp[t] - v;   // exclusive
    __syncthreads();
}

__device__ __forceinline__ int getI(const int* __restrict__ I,
                                    const int* __restrict__ bofs, size_t idx) {
    return I[idx] + bofs[idx >> 11];    // 2048-element scan chunks
}

__global__ void __launch_bounds__(256)
hist1_kernel(const int* __restrict__ row, int* __restrict__ hists,
             int E, int nbkt, int NB) {
    __shared__ int hist[MAXBKT];
    for (int i = threadIdx.x; i < nbkt; i += 256) hist[i] = 0;
    __syncthreads();
    int e0 = blockIdx.x * CHUNK;
    int e1 = min(e0 + CHUNK, E);
    for (int e = e0 + threadIdx.x; e < e1; e += 256)
        atomicAdd(&hist[row[e] >> BKT_BITS], 1);            // LDS atomic
    __syncthreads();
    for (int i = threadIdx.x; i < nbkt; i += 256)
        hists[(size_t)i * NB + blockIdx.x] = hist[i];
}

__global__ void __launch_bounds__(SCAN_T)
scan1_kernel(int* __restrict__ I, int* __restrict__ bsum, int T) {
    __shared__ int lds[SCAN_T];
    int t = threadIdx.x;
    int base = blockIdx.x * SCAN_CHUNK + t * SCAN_PER;
    int v[SCAN_PER];
    int run = 0;
#pragma unroll
    for (int j = 0; j < SCAN_PER; ++j) {
        int i = base + j;
        run += (i < T) ? I[i] : 0;
        v[j] = run;
    }
    lds[t] = run;
    __syncthreads();
    for (int off = 1; off < SCAN_T; off <<= 1) {
        int add = (t >= off) ? lds[t - off] : 0;
        __syncthreads();
        lds[t] += add;
        __syncthreads();
    }
    int excl = lds[t] - run;
#pragma unroll
    for (int j = 0; j < SCAN_PER; ++j) {
        int i = base + j;
        if (i < T) I[i] = v[j] + excl;
    }
    if (t == SCAN_T - 1) bsum[blockIdx.x] = lds[t];
}

__global__ void __launch_bounds__(256)
place1_kernel(const int* __restrict__ row, const int* __restrict__ col,
              const float* __restrict__ w, const int* __restrict__ I,
              const int* __restrict__ bsum, int nsc, int2* __restrict__ eb1,
              int E, int nbkt, int NB) {
    __shared__ int srow[CHUNK];
    __shared__ int hist[MAXBKT];
    __shared__ int tmp[MAXNSC];
    __shared__ int bofs[MAXNSC];
    build_bofs(bsum, nsc, tmp, bofs);
    for (int i = threadIdx.x; i < nbkt; i += 256) hist[i] = 0;
    int e0 = blockIdx.x * CHUNK;
    int e1 = min(e0 + CHUNK, E);
    for (int e = e0 + threadIdx.x; e < e1; e += 256) srow[e - e0] = row[e];
    __syncthreads();
    for (int i = threadIdx.x; i < e1 - e0; i += 256)
        atomicAdd(&hist[srow[i] >> BKT_BITS], 1);
    __syncthreads();
    for (int i = threadIdx.x; i < nbkt; i += 256) {
        size_t idx = (size_t)i * NB + blockIdx.x;
        hist[i] = getI(I, bofs, idx) - hist[i];
    }
    __syncthreads();
    for (int e = e0 + threadIdx.x; e < e1; e += 256) {
        int r = srow[e - e0];
        int pos = atomicAdd(&hist[r >> BKT_BITS], 1);        // LDS atomic, returns slot
        eb1[pos] = make_int2(((r & (BKTSZ - 1)) << 20) | col[e], __float_as_int(w[e]));
    }
}

__global__ void __launch_bounds__(256)
place2_kernel(const int2* __restrict__ eb1, const int* __restrict__ I,
              const int* __restrict__ bsum, int nsc, int2* __restrict__ edges,
              int* __restrict__ rs, int N, int NB) {
    __shared__ int hist[BKTSZ];
    __shared__ int scanv[BKTSZ];
    __shared__ int tmp[MAXNSC];
    __shared__ int bofs[MAXNSC];
    build_bofs(bsum, nsc, tmp, bofs);
    int b = blockIdx.x;
    int t = threadIdx.x;
    int bstart = (b == 0) ? 0 : getI(I, bofs, (size_t)b * NB - 1);
    int bend   = getI(I, bofs, (size_t)(b + 1) * NB - 1);
    if (t < BKTSZ) hist[t] = 0;
    __syncthreads();
    for (int e = bstart + t; e < bend; e += 256)
        atomicAdd(&hist[(eb1[e].x >> 20) & (BKTSZ - 1)], 1);
    __syncthreads();
    int cval = (t < BKTSZ) ? hist[t] : 0;
    if (t < BKTSZ) scanv[t] = cval;
    __syncthreads();
    for (int off = 1; off < BKTSZ; off <<= 1) {
        int add = (t < BKTSZ && t >= off) ? scanv[t - off] : 0;
        __syncthreads();
        if (t < BKTSZ) scanv[t] += add;
        __syncthreads();
    }
    if (t < BKTSZ) {
        int gnode = b * BKTSZ + t;
        if (gnode < N) rs[gnode] = bstart + scanv[t];        // inclusive ends
        hist[t] = bstart + scanv[t] - cval;                  // node base for placing
    }
    __syncthreads();
    for (int e = bstart + t; e < bend; e += 256) {
        int2 ev = eb1[e];
        int lrow = (ev.x >> 20) & (BKTSZ - 1);
        int pos = atomicAdd(&hist[lrow], 1);                 // LDS atomic
        edges[pos] = make_int2(ev.x & 0xFFFFF, ev.y);        // {col, w_bits}
    }
}

// ---------------- MFMA dense transform: out = in @ W  (bf16 out) ----------------
// Wave = 16-node x M tile via v_mfma_f32_16x16x32_bf16. A: row=lane&15,
// k=(lane>>4)*8+j. B: col=lane&15, k=(lane>>4)*8+j. D: col=lane&15,
// row=(lane>>4)*4+reg (verified layout, learn_hip m89). B-frags are
// loop-invariant; NT node-tiles per wave amortize their setup.

template <int K, int M, int NT, bool INF32>
__global__ void __launch_bounds__(256)
mfma_gemm_kernel(const void* __restrict__ inv, const float* __restrict__ W,
                 __hip_bfloat16* __restrict__ out, int N) {
    constexpr int CT = M / 16;   // col tiles
    constexpr int KH = K / 32;   // K halves
    __shared__ float Ws[K * M];
    for (int i = threadIdx.x; i < K * M / 4; i += 256)
        reinterpret_cast<float4*>(Ws)[i] = reinterpret_cast<const float4*>(W)[i];
    __syncthreads();

    const int lane = threadIdx.x & 63;
    const int wave = threadIdx.x >> 6;
    const int lrow = lane & 15;
    const int lgrp = lane >> 4;

    // B fragments: bfrag[ct][kh][j] = W[kh*32 + lgrp*8 + j][ct*16 + lrow]
    bf16x8 bfrag[CT][KH];
#pragma unroll
    for (int ct = 0; ct < CT; ++ct)
#pragma unroll
        for (int kh = 0; kh < KH; ++kh)
#pragma unroll
            for (int j = 0; j < 8; ++j)
                bfrag[ct][kh][j] =
                    (short)f2bf(Ws[(kh * 32 + lgrp * 8 + j) * M + ct * 16 + lrow]);

    const float* inf = (const float*)inv;
    const unsigned short* inb = (const unsigned short*)inv;
    unsigned short* outs = (unsigned short*)out;

    const int wave_base = blockIdx.x * (4 * NT * 16) + wave * (NT * 16);
#pragma unroll
    for (int t = 0; t < NT; ++t) {
        int nb = wave_base + t * 16;
        if (nb >= N) break;                       // N % 16 == 0: tiles are full
        int arow = nb + lrow;

        bf16x8 afrag[KH];
#pragma unroll
        for (int kh = 0; kh < KH; ++kh) {
            if constexpr (INF32) {
                const float* ap = inf + (size_t)arow * K + kh * 32 + lgrp * 8;
                float4 u0 = *reinterpret_cast<const float4*>(ap);
                float4 u1 = *reinterpret_cast<const float4*>(ap + 4);
                afrag[kh][0] = (short)f2bf(u0.x); afrag[kh][1] = (short)f2bf(u0.y);
                afrag[kh][2] = (short)f2bf(u0.z); afrag[kh][3] = (short)f2bf(u0.w);
                afrag[kh][4] = (short)f2bf(u1.x); afrag[kh][5] = (short)f2bf(u1.y);
                afrag[kh][6] = (short)f2bf(u1.z); afrag[kh][7] = (short)f2bf(u1.w);
            } else {
                afrag[kh] = *reinterpret_cast<const bf16x8*>(
                    inb + (size_t)arow * K + kh * 32 + lgrp * 8);   // 16B load
            }
        }

        f32x4 acc[CT];
#pragma unroll
        for (int ct = 0; ct < CT; ++ct) { acc[ct][0]=0.f; acc[ct][1]=0.f; acc[ct][2]=0.f; acc[ct][3]=0.f; }
#pragma unroll
        for (int ct = 0; ct < CT; ++ct)
#pragma unroll
            for (int kh = 0; kh < KH; ++kh)
                acc[ct] = __builtin_amdgcn_mfma_f32_16x16x32_bf16(
                    afrag[kh], bfrag[ct][kh], acc[ct], 0, 0, 0);

#pragma unroll
        for (int ct = 0; ct < CT; ++ct)
#pragma unroll
            for (int r = 0; r < 4; ++r) {
                int orow = nb + lgrp * 4 + r;
                outs[(size_t)orow * M + ct * 16 + lrow] = f2bf(acc[ct][r]);
            }
    }
}

// ---------------- CSR aggregation: wide gathers, G = M/VPT lanes per node ----------------

template <int M, int G, bool ACTOUT, bool OUTBF16>
__global__ void __launch_bounds__(256)
agg_kernel(const int* __restrict__ rs, const int2* __restrict__ edges,
           const __hip_bfloat16* __restrict__ sup, const float* __restrict__ b,
           void* __restrict__ outv, int N) {
    constexpr int VPT = M / G;
    static_assert(VPT == 8 || VPT == 4, "VPT must be 8 or 4");
    int tid = blockIdx.x * blockDim.x + threadIdx.x;
    int node = tid / G;
    if (node >= N) return;
    int g = tid - node * G;

    float acc[VPT];
#pragma unroll
    for (int j = 0; j < VPT; ++j) acc[j] = b[g * VPT + j];

    int beg = node ? rs[node - 1] : 0;
    int end = rs[node];
    const unsigned short* su = reinterpret_cast<const unsigned short*>(sup) + g * VPT;

    for (int j0 = beg; j0 < end; j0 += G) {
        int jl = j0 + g;
        int2 ev = edges[jl < end ? jl : end - 1];   // coalesced; clamped lanes never broadcast
        int cnt = min(G, end - j0);
#pragma unroll 4
        for (int jj = 0; jj < cnt; ++jj) {
            int   col = __shfl(ev.x, jj, G);
            float w   = __int_as_float(__shfl(ev.y, jj, G));
            const unsigned short* p = su + (size_t)col * M;
            if constexpr (VPT == 8) {
                uint4 u = *reinterpret_cast<const uint4*>(p);   // 8 bf16 = 16B/lane
                acc[0] += w * bflo(u.x); acc[1] += w * bfhi(u.x);
                acc[2] += w * bflo(u.y); acc[3] += w * bfhi(u.y);
                acc[4] += w * bflo(u.z); acc[5] += w * bfhi(u.z);
                acc[6] += w * bflo(u.w); acc[7] += w * bfhi(u.w);
            } else {
                uint2 u = *reinterpret_cast<const uint2*>(p);   // 4 bf16 = 8B/lane
                acc[0] += w * bflo(u.x); acc[1] += w * bfhi(u.x);
                acc[2] += w * bflo(u.y); acc[3] += w * bfhi(u.y);
            }
        }
    }
    if (ACTOUT) {
#pragma unroll
        for (int j = 0; j < VPT; ++j) acc[j] = lrelu(acc[j]);
    }
    if constexpr (OUTBF16) {
        __hip_bfloat16* out = (__hip_bfloat16*)outv;
        if constexpr (VPT == 8) {
            uint4 o = { packbf(acc[0], acc[1]), packbf(acc[2], acc[3]),
                        packbf(acc[4], acc[5]), packbf(acc[6], acc[7]) };
            *reinterpret_cast<uint4*>(out + (size_t)node * M + g * 8) = o;
        } else {
            uint2 o = { packbf(acc[0], acc[1]), packbf(acc[2], acc[3]) };
            *reinterpret_cast<uint2*>(out + (size_t)node * M + g * 4) = o;
        }
    } else {
        float* out = (float*)outv;
        if constexpr (VPT == 8) {
            float4 o0 = {acc[0], acc[1], acc[2], acc[3]};
            float4 o1 = {acc[4], acc[5], acc[6], acc[7]};
            reinterpret_cast<float4*>(out + (size_t)node * M + g * 8)[0] = o0;
            reinterpret_cast<float4*>(out + (size_t)node * M + g * 8)[1] = o1;
        } else {
            float4 o = {acc[0], acc[1], acc[2], acc[3]};
            *reinterpret_cast<float4*>(out + (size_t)node * M + g * 4) = o;
        }
    }
}

extern "C" void kernel_launch(void* const* d_in, const int* in_sizes, int n_in,
                              void* d_out, int out_size, void* d_ws, size_t ws_size,
                              hipStream_t stream) {
    const float* x    = (const float*)d_in[0];
    const int*   erow = (const int*)  d_in[1];
    const int*   ecol = (const int*)  d_in[2];
    const float* ew   = (const float*)d_in[3];
    const float* W1   = (const float*)d_in[4];
    const float* b1   = (const float*)d_in[5];
    const float* W2   = (const float*)d_in[6];
    const float* b2   = (const float*)d_in[7];
    const float* W3   = (const float*)d_in[8];
    const float* b3   = (const float*)d_in[9];
    float* out = (float*)d_out;

    const int N = in_sizes[0] / 64;   // 100000
    const int E = in_sizes[1];        // 1000000

    auto cdiv = [](long a, long b) { return (int)((a + b - 1) / b); };
    const int NB   = cdiv(E, CHUNK);          // 245 edge chunks
    const int nbkt = cdiv(N, BKTSZ);          // 782 buckets
    const long T   = (long)nbkt * NB;         // 191,590 flat hist entries
    const int nsc  = cdiv(T, SCAN_CHUNK);     // 94 scan chunks (<= MAXNSC)

    // Workspace:
    //   [0,      12.8MB)  s1 (N*64 bf16); later s3 (N*16 bf16)
    //   [12.8,   25.6MB)  a1 (N*64 bf16); later a2 (N*32 bf16)
    //   [25.6,   32.0MB)  s2 (N*32 bf16)
    //   [32.0MB, ...)     I[T] (0.8MB), bsum[128], rs[N] (0.4MB),
    //                     eb1[E] int2 (8MB), edges[E] int2 (8MB)
    char* wsc = (char*)d_ws;
    const size_t SZ64B = (size_t)N * 64 * 2;   // 12.8 MB
    const size_t SZ32B = (size_t)N * 32 * 2;   // 6.4 MB
    __hip_bfloat16* s1 = (__hip_bfloat16*)(wsc);
    __hip_bfloat16* a1 = (__hip_bfloat16*)(wsc + SZ64B);
    __hip_bfloat16* s2 = (__hip_bfloat16*)(wsc + 2 * SZ64B);
    __hip_bfloat16* a2 = (__hip_bfloat16*)(wsc + SZ64B);          // reuse a1 (dead)
    __hip_bfloat16* s3 = (__hip_bfloat16*)(wsc);                  // reuse s1 (dead)

    char* csr = wsc + 2 * SZ64B + SZ32B;
    int*  I     = (int*)csr;                       // T ints
    int*  bsum  = I + T;                           // MAXNSC ints
    int*  rs    = bsum + MAXNSC;                   // N ints
    int2* eb1   = (int2*)(rs + N);                 // E int2
    int2* edges = eb1 + E;                         // E int2

    const int B = 256;
    constexpr int NT = 2;                          // node-tiles per wave
    const int GB = cdiv(N, 4 * NT * 16);           // 782 gemm blocks

    // ---- CSR build (no global atomics) ----
    hist1_kernel<<<NB, B, 0, stream>>>(erow, I, E, nbkt, NB);
    scan1_kernel<<<nsc, SCAN_T, 0, stream>>>(I, bsum, (int)T);
    place1_kernel<<<NB, B, 0, stream>>>(erow, ecol, ew, I, bsum, nsc, eb1, E, nbkt, NB);
    place2_kernel<<<nbkt, B, 0, stream>>>(eb1, I, bsum, nsc, edges, rs, N, NB);

    // ---- Layer 1: 64 -> 64 (x f32 -> cvt bf16 on load) ----
    mfma_gemm_kernel<64, 64, NT, true><<<GB, B, 0, stream>>>(x, W1, s1, N);
    agg_kernel<64, 8, true, true><<<cdiv((long)N * 8, B), B, 0, stream>>>(rs, edges, s1, b1, a1, N);

    // ---- Layer 2: 64 -> 32 ----
    mfma_gemm_kernel<64, 32, NT, false><<<GB, B, 0, stream>>>(a1, W2, s2, N);
    agg_kernel<32, 4, true, true><<<cdiv((long)N * 4, B), B, 0, stream>>>(rs, edges, s2, b2, a2, N);

    // ---- Layer 3: 32 -> 16 (final lrelu fused into agg) ----
    mfma_gemm_kernel<32, 16, NT, false><<<GB, B, 0, stream>>>(a2, W3, s3, N);
    agg_kernel<16, 4, true, false><<<cdiv((long)N * 4, B), B, 0, stream>>>(rs, edges, s3, b3, out, N);
}

// Round 12
// 106.908 us; speedup vs baseline: 1.5090x; 1.1073x over previous
//
#include <hip/hip_runtime.h>
#include <hip/hip_bf16.h>

// 3-layer GCN, N=100000, E=1000000, dims 64 -> 64 -> 32 -> 16.
// s_k = a_{k-1} @ W_k via MFMA (bf16); a_k = lrelu(b_k + segsum(w_e * s_k[col]))
// stored bf16 (f32 for final). CSR via two-level LDS bucket counting sort.
// R12: agg inner loop batches 8 edges, prefetches ALL 8 gathers before
// accumulating (MLP 4->8 vs R11's unroll-4 chain); final edge records packed
// to 4B: (w as 15-bit fixed [0,1)) << 17 | col (17 bits) -> one shfl/edge,
// half the edge-stream and place2-write traffic. w quant error ~3e-5 rel.

typedef short bf16x8 __attribute__((ext_vector_type(8)));
typedef float f32x4 __attribute__((ext_vector_type(4)));

__device__ __forceinline__ float lrelu(float v) { return v > 0.0f ? v : 0.25f * v; }
__device__ __forceinline__ float bflo(unsigned u) { return __uint_as_float(u << 16); }
__device__ __forceinline__ float bfhi(unsigned u) { return __uint_as_float(u & 0xffff0000u); }
__device__ __forceinline__ unsigned short f2bf(float f) {          // round-to-nearest-even
    unsigned u = __float_as_uint(f);
    return (unsigned short)((u + 0x7fffu + ((u >> 16) & 1u)) >> 16);
}
__device__ __forceinline__ unsigned packbf(float a, float b) {
    return (unsigned)f2bf(a) | ((unsigned)f2bf(b) << 16);
}

// ---------------- bucket counting-sort CSR build ----------------

constexpr int SCAN_T = 256;
constexpr int SCAN_PER = 8;
constexpr int SCAN_CHUNK = SCAN_T * SCAN_PER;  // 2048 (scan1 granularity; getI >>11)
constexpr int CHUNK = 4096;                    // edges per hist/place1 block
constexpr int BKT_BITS = 7;
constexpr int BKTSZ = 128;                     // nodes per bucket
constexpr int MAXBKT = 1024;                   // LDS bins (N <= 131072)
constexpr int MAXNSC = 128;                    // max scan1 chunks (T <= 262144)

__device__ __forceinline__ void build_bofs(const int* __restrict__ bsum, int nsc,
                                           int* tmp, int* bofs) {
    int t = threadIdx.x;
    int v = (t < MAXNSC && t < nsc) ? bsum[t] : 0;
    if (t < MAXNSC) tmp[t] = v;
    __syncthreads();
    for (int off = 1; off < MAXNSC; off <<= 1) {
        int add = (t < MAXNSC && t >= off) ? tmp[t - off] : 0;
        __syncthreads();
        if (t < MAXNSC) tmp[t] += add;
        __syncthreads();
    }
    if (t < MAXNSC) bofs[t] = tmp[t] - v;   // exclusive
    __syncthreads();
}

__device__ __forceinline__ int getI(const int* __restrict__ I,
                                    const int* __restrict__ bofs, size_t idx) {
    return I[idx] + bofs[idx >> 11];    // 2048-element scan chunks
}

__global__ void __launch_bounds__(256)
hist1_kernel(const int* __restrict__ row, int* __restrict__ hists,
             int E, int nbkt, int NB) {
    __shared__ int hist[MAXBKT];
    for (int i = threadIdx.x; i < nbkt; i += 256) hist[i] = 0;
    __syncthreads();
    int e0 = blockIdx.x * CHUNK;
    int e1 = min(e0 + CHUNK, E);
    for (int e = e0 + threadIdx.x; e < e1; e += 256)
        atomicAdd(&hist[row[e] >> BKT_BITS], 1);            // LDS atomic
    __syncthreads();
    for (int i = threadIdx.x; i < nbkt; i += 256)
        hists[(size_t)i * NB + blockIdx.x] = hist[i];
}

__global__ void __launch_bounds__(SCAN_T)
scan1_kernel(int* __restrict__ I, int* __restrict__ bsum, int T) {
    __shared__ int lds[SCAN_T];
    int t = threadIdx.x;
    int base = blockIdx.x * SCAN_CHUNK + t * SCAN_PER;
    int v[SCAN_PER];
    int run = 0;
#pragma unroll
    for (int j = 0; j < SCAN_PER; ++j) {
        int i = base + j;
        run += (i < T) ? I[i] : 0;
        v[j] = run;
    }
    lds[t] = run;
    __syncthreads();
    for (int off = 1; off < SCAN_T; off <<= 1) {
        int add = (t >= off) ? lds[t - off] : 0;
        __syncthreads();
        lds[t] += add;
        __syncthreads();
    }
    int excl = lds[t] - run;
#pragma unroll
    for (int j = 0; j < SCAN_PER; ++j) {
        int i = base + j;
        if (i < T) I[i] = v[j] + excl;
    }
    if (t == SCAN_T - 1) bsum[blockIdx.x] = lds[t];
}

__global__ void __launch_bounds__(256)
place1_kernel(const int* __restrict__ row, const int* __restrict__ col,
              const float* __restrict__ w, const int* __restrict__ I,
              const int* __restrict__ bsum, int nsc, int2* __restrict__ eb1,
              int E, int nbkt, int NB) {
    __shared__ int srow[CHUNK];
    __shared__ int hist[MAXBKT];
    __shared__ int tmp[MAXNSC];
    __shared__ int bofs[MAXNSC];
    build_bofs(bsum, nsc, tmp, bofs);
    for (int i = threadIdx.x; i < nbkt; i += 256) hist[i] = 0;
    int e0 = blockIdx.x * CHUNK;
    int e1 = min(e0 + CHUNK, E);
    for (int e = e0 + threadIdx.x; e < e1; e += 256) srow[e - e0] = row[e];
    __syncthreads();
    for (int i = threadIdx.x; i < e1 - e0; i += 256)
        atomicAdd(&hist[srow[i] >> BKT_BITS], 1);
    __syncthreads();
    for (int i = threadIdx.x; i < nbkt; i += 256) {
        size_t idx = (size_t)i * NB + blockIdx.x;
        hist[i] = getI(I, bofs, idx) - hist[i];
    }
    __syncthreads();
    for (int e = e0 + threadIdx.x; e < e1; e += 256) {
        int r = srow[e - e0];
        int pos = atomicAdd(&hist[r >> BKT_BITS], 1);        // LDS atomic, returns slot
        eb1[pos] = make_int2(((r & (BKTSZ - 1)) << 20) | col[e], __float_as_int(w[e]));
    }
}

// one block per bucket: per-node CSR within the bucket; emits 4B-packed edges[] + rs[].
__global__ void __launch_bounds__(256)
place2_kernel(const int2* __restrict__ eb1, const int* __restrict__ I,
              const int* __restrict__ bsum, int nsc, unsigned* __restrict__ edges,
              int* __restrict__ rs, int N, int NB) {
    __shared__ int hist[BKTSZ];
    __shared__ int scanv[BKTSZ];
    __shared__ int tmp[MAXNSC];
    __shared__ int bofs[MAXNSC];
    build_bofs(bsum, nsc, tmp, bofs);
    int b = blockIdx.x;
    int t = threadIdx.x;
    int bstart = (b == 0) ? 0 : getI(I, bofs, (size_t)b * NB - 1);
    int bend   = getI(I, bofs, (size_t)(b + 1) * NB - 1);
    if (t < BKTSZ) hist[t] = 0;
    __syncthreads();
    for (int e = bstart + t; e < bend; e += 256)
        atomicAdd(&hist[(eb1[e].x >> 20) & (BKTSZ - 1)], 1);
    __syncthreads();
    int cval = (t < BKTSZ) ? hist[t] : 0;
    if (t < BKTSZ) scanv[t] = cval;
    __syncthreads();
    for (int off = 1; off < BKTSZ; off <<= 1) {
        int add = (t < BKTSZ && t >= off) ? scanv[t - off] : 0;
        __syncthreads();
        if (t < BKTSZ) scanv[t] += add;
        __syncthreads();
    }
    if (t < BKTSZ) {
        int gnode = b * BKTSZ + t;
        if (gnode < N) rs[gnode] = bstart + scanv[t];        // inclusive ends
        hist[t] = bstart + scanv[t] - cval;                  // node base for placing
    }
    __syncthreads();
    for (int e = bstart + t; e < bend; e += 256) {
        int2 ev = eb1[e];
        int lrow = (ev.x >> 20) & (BKTSZ - 1);
        float w = __int_as_float(ev.y);
        unsigned q = (unsigned)(w * 32768.f + 0.5f);
        q = q > 32767u ? 32767u : q;
        unsigned packed = (q << 17) | (unsigned)(ev.x & 0x1FFFF);   // w15 | col17
        int pos = atomicAdd(&hist[lrow], 1);                 // LDS atomic
        edges[pos] = packed;
    }
}

// ---------------- MFMA dense transform: out = in @ W  (bf16 out) ----------------

template <int K, int M, int NT, bool INF32>
__global__ void __launch_bounds__(256)
mfma_gemm_kernel(const void* __restrict__ inv, const float* __restrict__ W,
                 __hip_bfloat16* __restrict__ out, int N) {
    constexpr int CT = M / 16;   // col tiles
    constexpr int KH = K / 32;   // K halves
    __shared__ float Ws[K * M];
    for (int i = threadIdx.x; i < K * M / 4; i += 256)
        reinterpret_cast<float4*>(Ws)[i] = reinterpret_cast<const float4*>(W)[i];
    __syncthreads();

    const int lane = threadIdx.x & 63;
    const int wave = threadIdx.x >> 6;
    const int lrow = lane & 15;
    const int lgrp = lane >> 4;

    bf16x8 bfrag[CT][KH];
#pragma unroll
    for (int ct = 0; ct < CT; ++ct)
#pragma unroll
        for (int kh = 0; kh < KH; ++kh)
#pragma unroll
            for (int j = 0; j < 8; ++j)
                bfrag[ct][kh][j] =
                    (short)f2bf(Ws[(kh * 32 + lgrp * 8 + j) * M + ct * 16 + lrow]);

    const float* inf = (const float*)inv;
    const unsigned short* inb = (const unsigned short*)inv;
    unsigned short* outs = (unsigned short*)out;

    const int wave_base = blockIdx.x * (4 * NT * 16) + wave * (NT * 16);
#pragma unroll
    for (int t = 0; t < NT; ++t) {
        int nb = wave_base + t * 16;
        if (nb >= N) break;
        int arow = nb + lrow;

        bf16x8 afrag[KH];
#pragma unroll
        for (int kh = 0; kh < KH; ++kh) {
            if constexpr (INF32) {
                const float* ap = inf + (size_t)arow * K + kh * 32 + lgrp * 8;
                float4 u0 = *reinterpret_cast<const float4*>(ap);
                float4 u1 = *reinterpret_cast<const float4*>(ap + 4);
                afrag[kh][0] = (short)f2bf(u0.x); afrag[kh][1] = (short)f2bf(u0.y);
                afrag[kh][2] = (short)f2bf(u0.z); afrag[kh][3] = (short)f2bf(u0.w);
                afrag[kh][4] = (short)f2bf(u1.x); afrag[kh][5] = (short)f2bf(u1.y);
                afrag[kh][6] = (short)f2bf(u1.z); afrag[kh][7] = (short)f2bf(u1.w);
            } else {
                afrag[kh] = *reinterpret_cast<const bf16x8*>(
                    inb + (size_t)arow * K + kh * 32 + lgrp * 8);   // 16B load
            }
        }

        f32x4 acc[CT];
#pragma unroll
        for (int ct = 0; ct < CT; ++ct) { acc[ct][0]=0.f; acc[ct][1]=0.f; acc[ct][2]=0.f; acc[ct][3]=0.f; }
#pragma unroll
        for (int ct = 0; ct < CT; ++ct)
#pragma unroll
            for (int kh = 0; kh < KH; ++kh)
                acc[ct] = __builtin_amdgcn_mfma_f32_16x16x32_bf16(
                    afrag[kh], bfrag[ct][kh], acc[ct], 0, 0, 0);

#pragma unroll
        for (int ct = 0; ct < CT; ++ct)
#pragma unroll
            for (int r = 0; r < 4; ++r) {
                int orow = nb + lgrp * 4 + r;
                outs[(size_t)orow * M + ct * 16 + lrow] = f2bf(acc[ct][r]);
            }
    }
}

// ---------------- CSR aggregation: 8-edge batches, prefetch-all gathers ----------------
// G lanes per node; per iteration the group loads 8 packed edges (NE=8/G per
// lane, coalesced), issues all 8 independent row-gathers, then accumulates.

template <int M, int G, bool ACTOUT, bool OUTBF16>
__global__ void __launch_bounds__(256)
agg_kernel(const int* __restrict__ rs, const unsigned* __restrict__ edges,
           const __hip_bfloat16* __restrict__ sup, const float* __restrict__ b,
           void* __restrict__ outv, int N) {
    constexpr int VPT = M / G;
    constexpr int EB = 8;            // edges per batch (gathers in flight)
    constexpr int NE = EB / G;       // edge loads per lane
    static_assert(VPT == 8 || VPT == 4, "VPT must be 8 or 4");
    int tid = blockIdx.x * blockDim.x + threadIdx.x;
    int node = tid / G;
    if (node >= N) return;
    int g = tid - node * G;

    float acc[VPT];
#pragma unroll
    for (int j = 0; j < VPT; ++j) acc[j] = b[g * VPT + j];

    int beg = node ? rs[node - 1] : 0;
    int end = rs[node];
    const unsigned short* su = reinterpret_cast<const unsigned short*>(sup) + g * VPT;

    using gvec = typename std::conditional<VPT == 8, uint4, uint2>::type;

    for (int j0 = beg; j0 < end; j0 += EB) {
        unsigned p[NE];
#pragma unroll
        for (int k = 0; k < NE; ++k) {
            int jl = j0 + k * G + g;
            p[k] = edges[jl < end ? jl : end - 1];   // coalesced; clamped never used
        }
        int cnt = min(EB, end - j0);
        gvec gv[EB];
        float wv[EB];
#pragma unroll
        for (int jj = 0; jj < EB; ++jj) {
            unsigned pe = __shfl(p[jj / G], jj % G, G);      // one shfl per edge
            wv[jj] = (float)(pe >> 17) * (1.0f / 32768.f);
            unsigned col = pe & 0x1FFFFu;
            if (jj < cnt)
                gv[jj] = *reinterpret_cast<const gvec*>(su + (size_t)col * M);
        }
#pragma unroll
        for (int jj = 0; jj < EB; ++jj) {
            if (jj >= cnt) break;
            float w = wv[jj];
            if constexpr (VPT == 8) {
                acc[0] += w * bflo(gv[jj].x); acc[1] += w * bfhi(gv[jj].x);
                acc[2] += w * bflo(gv[jj].y); acc[3] += w * bfhi(gv[jj].y);
                acc[4] += w * bflo(gv[jj].z); acc[5] += w * bfhi(gv[jj].z);
                acc[6] += w * bflo(gv[jj].w); acc[7] += w * bfhi(gv[jj].w);
            } else {
                acc[0] += w * bflo(gv[jj].x); acc[1] += w * bfhi(gv[jj].x);
                acc[2] += w * bflo(gv[jj].y); acc[3] += w * bfhi(gv[jj].y);
            }
        }
    }
    if (ACTOUT) {
#pragma unroll
        for (int j = 0; j < VPT; ++j) acc[j] = lrelu(acc[j]);
    }
    if constexpr (OUTBF16) {
        __hip_bfloat16* out = (__hip_bfloat16*)outv;
        if constexpr (VPT == 8) {
            uint4 o = { packbf(acc[0], acc[1]), packbf(acc[2], acc[3]),
                        packbf(acc[4], acc[5]), packbf(acc[6], acc[7]) };
            *reinterpret_cast<uint4*>(out + (size_t)node * M + g * 8) = o;
        } else {
            uint2 o = { packbf(acc[0], acc[1]), packbf(acc[2], acc[3]) };
            *reinterpret_cast<uint2*>(out + (size_t)node * M + g * 4) = o;
        }
    } else {
        float* out = (float*)outv;
        if constexpr (VPT == 8) {
            float4 o0 = {acc[0], acc[1], acc[2], acc[3]};
            float4 o1 = {acc[4], acc[5], acc[6], acc[7]};
            reinterpret_cast<float4*>(out + (size_t)node * M + g * 8)[0] = o0;
            reinterpret_cast<float4*>(out + (size_t)node * M + g * 8)[1] = o1;
        } else {
            float4 o = {acc[0], acc[1], acc[2], acc[3]};
            *reinterpret_cast<float4*>(out + (size_t)node * M + g * 4) = o;
        }
    }
}

extern "C" void kernel_launch(void* const* d_in, const int* in_sizes, int n_in,
                              void* d_out, int out_size, void* d_ws, size_t ws_size,
                              hipStream_t stream) {
    const float* x    = (const float*)d_in[0];
    const int*   erow = (const int*)  d_in[1];
    const int*   ecol = (const int*)  d_in[2];
    const float* ew   = (const float*)d_in[3];
    const float* W1   = (const float*)d_in[4];
    const float* b1   = (const float*)d_in[5];
    const float* W2   = (const float*)d_in[6];
    const float* b2   = (const float*)d_in[7];
    const float* W3   = (const float*)d_in[8];
    const float* b3   = (const float*)d_in[9];
    float* out = (float*)d_out;

    const int N = in_sizes[0] / 64;   // 100000
    const int E = in_sizes[1];        // 1000000

    auto cdiv = [](long a, long b) { return (int)((a + b - 1) / b); };
    const int NB   = cdiv(E, CHUNK);          // 245 edge chunks
    const int nbkt = cdiv(N, BKTSZ);          // 782 buckets
    const long T   = (long)nbkt * NB;         // 191,590 flat hist entries
    const int nsc  = cdiv(T, SCAN_CHUNK);     // 94 scan chunks (<= MAXNSC)

    // Workspace:
    //   [0,      12.8MB)  s1 (N*64 bf16); later s3 (N*16 bf16)
    //   [12.8,   25.6MB)  a1 (N*64 bf16); later a2 (N*32 bf16)
    //   [25.6,   32.0MB)  s2 (N*32 bf16)
    //   [32.0MB, ...)     I[T] (0.8MB), bsum[128], rs[N] (0.4MB),
    //                     eb1[E] int2 (8MB), edges[E] uint (4MB)
    char* wsc = (char*)d_ws;
    const size_t SZ64B = (size_t)N * 64 * 2;   // 12.8 MB
    const size_t SZ32B = (size_t)N * 32 * 2;   // 6.4 MB
    __hip_bfloat16* s1 = (__hip_bfloat16*)(wsc);
    __hip_bfloat16* a1 = (__hip_bfloat16*)(wsc + SZ64B);
    __hip_bfloat16* s2 = (__hip_bfloat16*)(wsc + 2 * SZ64B);
    __hip_bfloat16* a2 = (__hip_bfloat16*)(wsc + SZ64B);          // reuse a1 (dead)
    __hip_bfloat16* s3 = (__hip_bfloat16*)(wsc);                  // reuse s1 (dead)

    char* csr = wsc + 2 * SZ64B + SZ32B;
    int*      I     = (int*)csr;                   // T ints
    int*      bsum  = I + T;                       // MAXNSC ints
    int*      rs    = bsum + MAXNSC;               // N ints
    int2*     eb1   = (int2*)(rs + N);             // E int2
    unsigned* edges = (unsigned*)(eb1 + E);        // E uint (4B packed)

    const int B = 256;
    constexpr int NT = 2;                          // node-tiles per wave
    const int GB = cdiv(N, 4 * NT * 16);           // 782 gemm blocks

    // ---- CSR build (no global atomics) ----
    hist1_kernel<<<NB, B, 0, stream>>>(erow, I, E, nbkt, NB);
    scan1_kernel<<<nsc, SCAN_T, 0, stream>>>(I, bsum, (int)T);
    place1_kernel<<<NB, B, 0, stream>>>(erow, ecol, ew, I, bsum, nsc, eb1, E, nbkt, NB);
    place2_kernel<<<nbkt, B, 0, stream>>>(eb1, I, bsum, nsc, edges, rs, N, NB);

    // ---- Layer 1: 64 -> 64 (x f32 -> cvt bf16 on load) ----
    mfma_gemm_kernel<64, 64, NT, true><<<GB, B, 0, stream>>>(x, W1, s1, N);
    agg_kernel<64, 8, true, true><<<cdiv((long)N * 8, B), B, 0, stream>>>(rs, edges, s1, b1, a1, N);

    // ---- Layer 2: 64 -> 32 ----
    mfma_gemm_kernel<64, 32, NT, false><<<GB, B, 0, stream>>>(a1, W2, s2, N);
    agg_kernel<32, 4, true, true><<<cdiv((long)N * 4, B), B, 0, stream>>>(rs, edges, s2, b2, a2, N);

    // ---- Layer 3: 32 -> 16 (final lrelu fused into agg) ----
    mfma_gemm_kernel<32, 16, NT, false><<<GB, B, 0, stream>>>(a2, W3, s3, N);
    agg_kernel<16, 4, true, false><<<cdiv((long)N * 4, B), B, 0, stream>>>(rs, edges, s3, b3, out, N);
}

// Round 13
// 95.932 us; speedup vs baseline: 1.6816x; 1.1144x over previous
//
#include <hip/hip_runtime.h>
#include <hip/hip_bf16.h>

// 3-layer GCN, N=100000, E=1000000, dims 64 -> 64 -> 32 -> 16.
// CSR via two-level LDS bucket counting sort (zero global atomics).
// R13: (a) agg_k + mfma_gemm_{k+1} fused: agg writes lrelu'd bf16 rows into a
// padded LDS tile, one barrier, MFMA phase consumes -> a1/a2 global arrays
// deleted (-38MB traffic, -2 dispatches). (b) hist1 fused into mfma_gemm1
// (R9's failure was the scalar gemm's own 140 VGPR, not fusion - R10 proved).
// 10 -> 7 dispatches. agg3/scan/place kernels unchanged.

typedef short bf16x8 __attribute__((ext_vector_type(8)));
typedef float f32x4 __attribute__((ext_vector_type(4)));

__device__ __forceinline__ float lrelu(float v) { return v > 0.0f ? v : 0.25f * v; }
__device__ __forceinline__ float bflo(unsigned u) { return __uint_as_float(u << 16); }
__device__ __forceinline__ float bfhi(unsigned u) { return __uint_as_float(u & 0xffff0000u); }
__device__ __forceinline__ unsigned short f2bf(float f) {          // round-to-nearest-even
    unsigned u = __float_as_uint(f);
    return (unsigned short)((u + 0x7fffu + ((u >> 16) & 1u)) >> 16);
}
__device__ __forceinline__ unsigned packbf(float a, float b) {
    return (unsigned)f2bf(a) | ((unsigned)f2bf(b) << 16);
}

// ---------------- bucket counting-sort CSR build ----------------

constexpr int SCAN_T = 256;
constexpr int SCAN_PER = 8;
constexpr int SCAN_CHUNK = SCAN_T * SCAN_PER;  // 2048 (scan1 granularity; getI >>11)
constexpr int CHUNK = 4096;                    // edges per hist/place1 block
constexpr int BKT_BITS = 7;
constexpr int BKTSZ = 128;                     // nodes per bucket
constexpr int MAXBKT = 1024;                   // LDS bins (N <= 131072)
constexpr int MAXNSC = 128;                    // max scan1 chunks (T <= 262144)

__device__ __forceinline__ void build_bofs(const int* __restrict__ bsum, int nsc,
                                           int* tmp, int* bofs) {
    int t = threadIdx.x;
    int v = (t < MAXNSC && t < nsc) ? bsum[t] : 0;
    if (t < MAXNSC) tmp[t] = v;
    __syncthreads();
    for (int off = 1; off < MAXNSC; off <<= 1) {
        int add = (t < MAXNSC && t >= off) ? tmp[t - off] : 0;
        __syncthreads();
        if (t < MAXNSC) tmp[t] += add;
        __syncthreads();
    }
    if (t < MAXNSC) bofs[t] = tmp[t] - v;   // exclusive
    __syncthreads();
}

__device__ __forceinline__ int getI(const int* __restrict__ I,
                                    const int* __restrict__ bofs, size_t idx) {
    return I[idx] + bofs[idx >> 11];    // 2048-element scan chunks
}

__global__ void __launch_bounds__(SCAN_T)
scan1_kernel(int* __restrict__ I, int* __restrict__ bsum, int T) {
    __shared__ int lds[SCAN_T];
    int t = threadIdx.x;
    int base = blockIdx.x * SCAN_CHUNK + t * SCAN_PER;
    int v[SCAN_PER];
    int run = 0;
#pragma unroll
    for (int j = 0; j < SCAN_PER; ++j) {
        int i = base + j;
        run += (i < T) ? I[i] : 0;
        v[j] = run;
    }
    lds[t] = run;
    __syncthreads();
    for (int off = 1; off < SCAN_T; off <<= 1) {
        int add = (t >= off) ? lds[t - off] : 0;
        __syncthreads();
        lds[t] += add;
        __syncthreads();
    }
    int excl = lds[t] - run;
#pragma unroll
    for (int j = 0; j < SCAN_PER; ++j) {
        int i = base + j;
        if (i < T) I[i] = v[j] + excl;
    }
    if (t == SCAN_T - 1) bsum[blockIdx.x] = lds[t];
}

__global__ void __launch_bounds__(256)
place1_kernel(const int* __restrict__ row, const int* __restrict__ col,
              const float* __restrict__ w, const int* __restrict__ I,
              const int* __restrict__ bsum, int nsc, int2* __restrict__ eb1,
              int E, int nbkt, int NB) {
    __shared__ int srow[CHUNK];
    __shared__ int hist[MAXBKT];
    __shared__ int tmp[MAXNSC];
    __shared__ int bofs[MAXNSC];
    build_bofs(bsum, nsc, tmp, bofs);
    for (int i = threadIdx.x; i < nbkt; i += 256) hist[i] = 0;
    int e0 = blockIdx.x * CHUNK;
    int e1 = min(e0 + CHUNK, E);
    for (int e = e0 + threadIdx.x; e < e1; e += 256) srow[e - e0] = row[e];
    __syncthreads();
    for (int i = threadIdx.x; i < e1 - e0; i += 256)
        atomicAdd(&hist[srow[i] >> BKT_BITS], 1);
    __syncthreads();
    for (int i = threadIdx.x; i < nbkt; i += 256) {
        size_t idx = (size_t)i * NB + blockIdx.x;
        hist[i] = getI(I, bofs, idx) - hist[i];
    }
    __syncthreads();
    for (int e = e0 + threadIdx.x; e < e1; e += 256) {
        int r = srow[e - e0];
        int pos = atomicAdd(&hist[r >> BKT_BITS], 1);        // LDS atomic, returns slot
        eb1[pos] = make_int2(((r & (BKTSZ - 1)) << 20) | col[e], __float_as_int(w[e]));
    }
}

// one block per bucket: per-node CSR within the bucket; emits 4B-packed edges[] + rs[].
__global__ void __launch_bounds__(256)
place2_kernel(const int2* __restrict__ eb1, const int* __restrict__ I,
              const int* __restrict__ bsum, int nsc, unsigned* __restrict__ edges,
              int* __restrict__ rs, int N, int NB) {
    __shared__ int hist[BKTSZ];
    __shared__ int scanv[BKTSZ];
    __shared__ int tmp[MAXNSC];
    __shared__ int bofs[MAXNSC];
    build_bofs(bsum, nsc, tmp, bofs);
    int b = blockIdx.x;
    int t = threadIdx.x;
    int bstart = (b == 0) ? 0 : getI(I, bofs, (size_t)b * NB - 1);
    int bend   = getI(I, bofs, (size_t)(b + 1) * NB - 1);
    if (t < BKTSZ) hist[t] = 0;
    __syncthreads();
    for (int e = bstart + t; e < bend; e += 256)
        atomicAdd(&hist[(eb1[e].x >> 20) & (BKTSZ - 1)], 1);
    __syncthreads();
    int cval = (t < BKTSZ) ? hist[t] : 0;
    if (t < BKTSZ) scanv[t] = cval;
    __syncthreads();
    for (int off = 1; off < BKTSZ; off <<= 1) {
        int add = (t < BKTSZ && t >= off) ? scanv[t - off] : 0;
        __syncthreads();
        if (t < BKTSZ) scanv[t] += add;
        __syncthreads();
    }
    if (t < BKTSZ) {
        int gnode = b * BKTSZ + t;
        if (gnode < N) rs[gnode] = bstart + scanv[t];        // inclusive ends
        hist[t] = bstart + scanv[t] - cval;                  // node base for placing
    }
    __syncthreads();
    for (int e = bstart + t; e < bend; e += 256) {
        int2 ev = eb1[e];
        int lrow = (ev.x >> 20) & (BKTSZ - 1);
        float w = __int_as_float(ev.y);
        unsigned q = (unsigned)(w * 32768.f + 0.5f);
        q = q > 32767u ? 32767u : q;
        unsigned packed = (q << 17) | (unsigned)(ev.x & 0x1FFFF);   // w15 | col17
        int pos = atomicAdd(&hist[lrow], 1);                 // LDS atomic
        edges[pos] = packed;
    }
}

// ---------------- fused: hist1 (blocks [0,NB)) + MFMA gemm1 (blocks [NB,..)) ----------------
// Both roles are lean (hist ~16 VGPR, mfma gemm ~70): co-compile is safe now.

__global__ void __launch_bounds__(256)
fused_hist_gemm1_kernel(const int* __restrict__ row, int* __restrict__ hists,
                        int E, int nbkt, int NB,
                        const float* __restrict__ x, const float* __restrict__ W1,
                        __hip_bfloat16* __restrict__ s1, int N) {
    __shared__ float Ws[64 * 64];   // 16KB; hist role reuses first 4KB as int bins
    if ((int)blockIdx.x < NB) {
        int* hist = reinterpret_cast<int*>(Ws);
        for (int i = threadIdx.x; i < nbkt; i += 256) hist[i] = 0;
        __syncthreads();
        int e0 = blockIdx.x * CHUNK;
        int e1 = min(e0 + CHUNK, E);
        for (int e = e0 + threadIdx.x; e < e1; e += 256)
            atomicAdd(&hist[row[e] >> BKT_BITS], 1);         // LDS atomic
        __syncthreads();
        for (int i = threadIdx.x; i < nbkt; i += 256)
            hists[(size_t)i * NB + blockIdx.x] = hist[i];
        return;
    }
    // ---- MFMA gemm1: s1 = bf16(x) @ W1, K=64, M=64, NT=2 node-tiles/wave ----
    constexpr int K = 64, M = 64, NT = 2, CT = M / 16, KH = K / 32;
    for (int i = threadIdx.x; i < K * M / 4; i += 256)
        reinterpret_cast<float4*>(Ws)[i] = reinterpret_cast<const float4*>(W1)[i];
    __syncthreads();
    const int lane = threadIdx.x & 63;
    const int wave = threadIdx.x >> 6;
    const int lrow = lane & 15;
    const int lgrp = lane >> 4;

    bf16x8 bfrag[CT][KH];
#pragma unroll
    for (int ct = 0; ct < CT; ++ct)
#pragma unroll
        for (int kh = 0; kh < KH; ++kh)
#pragma unroll
            for (int j = 0; j < 8; ++j)
                bfrag[ct][kh][j] =
                    (short)f2bf(Ws[(kh * 32 + lgrp * 8 + j) * M + ct * 16 + lrow]);

    unsigned short* outs = (unsigned short*)s1;
    const int wave_base = ((int)blockIdx.x - NB) * (4 * NT * 16) + wave * (NT * 16);
#pragma unroll
    for (int t = 0; t < NT; ++t) {
        int nb = wave_base + t * 16;
        if (nb >= N) break;
        int arow = nb + lrow;
        bf16x8 afrag[KH];
#pragma unroll
        for (int kh = 0; kh < KH; ++kh) {
            const float* ap = x + (size_t)arow * K + kh * 32 + lgrp * 8;
            float4 u0 = *reinterpret_cast<const float4*>(ap);
            float4 u1 = *reinterpret_cast<const float4*>(ap + 4);
            afrag[kh][0] = (short)f2bf(u0.x); afrag[kh][1] = (short)f2bf(u0.y);
            afrag[kh][2] = (short)f2bf(u0.z); afrag[kh][3] = (short)f2bf(u0.w);
            afrag[kh][4] = (short)f2bf(u1.x); afrag[kh][5] = (short)f2bf(u1.y);
            afrag[kh][6] = (short)f2bf(u1.z); afrag[kh][7] = (short)f2bf(u1.w);
        }
        f32x4 acc[CT];
#pragma unroll
        for (int ct = 0; ct < CT; ++ct) { acc[ct][0]=0.f; acc[ct][1]=0.f; acc[ct][2]=0.f; acc[ct][3]=0.f; }
#pragma unroll
        for (int ct = 0; ct < CT; ++ct)
#pragma unroll
            for (int kh = 0; kh < KH; ++kh)
                acc[ct] = __builtin_amdgcn_mfma_f32_16x16x32_bf16(
                    afrag[kh], bfrag[ct][kh], acc[ct], 0, 0, 0);
#pragma unroll
        for (int ct = 0; ct < CT; ++ct)
#pragma unroll
            for (int r = 0; r < 4; ++r) {
                int orow = nb + lgrp * 4 + r;
                outs[(size_t)orow * M + ct * 16 + lrow] = f2bf(acc[ct][r]);
            }
    }
}

// ---------------- fused agg_k + gemm_{k+1}: sup --gather--> LDS tile --MFMA--> outS ----
// Agg phase: GA lanes/node, VPT=8 bf16 cols each; bias+lrelu+pack -> LDS (padded rows).
// Gemm phase: wave (tile,ct) consumes 16-node LDS tiles via 16B reads + MFMA.
// MA = agg dim (= gemm K), MB = gemm out dim, NPB = nodes per block (= 256/GA).

template <int MA, int GA, int MB>
__global__ void __launch_bounds__(256)
fused_agg_gemm_kernel(const int* __restrict__ rs, const unsigned* __restrict__ edges,
                      const __hip_bfloat16* __restrict__ sup, const float* __restrict__ bias,
                      const float* __restrict__ W, __hip_bfloat16* __restrict__ outS, int N) {
    constexpr int VPT = MA / GA;      // = 8
    static_assert(VPT == 8, "agg phase assumes 8 bf16 per lane");
    constexpr int NPB = 256 / GA;     // nodes per block (32 or 64)
    constexpr int KH = MA / 32, CTB = MB / 16, TILES = NPB / 16;
    static_assert(TILES * CTB == 4, "4 waves must cover (tile,ct) space");
    constexpr int STR = MA + 8;       // LDS row stride in bf16 (144B/80B: 16B-aligned)
    constexpr int EB = 8, NE = EB / GA;

    __shared__ float WsF[MA * MB];
    __shared__ unsigned short atile[NPB][STR];

    for (int i = threadIdx.x; i < MA * MB / 4; i += 256)
        reinterpret_cast<float4*>(WsF)[i] = reinterpret_cast<const float4*>(W)[i];

    // ---- agg phase ----
    int tid = threadIdx.x;
    int lr = tid / GA;                // local node row
    int g = tid & (GA - 1);
    int node = blockIdx.x * NPB + lr;

    float acc[VPT];
#pragma unroll
    for (int j = 0; j < VPT; ++j) acc[j] = bias[g * VPT + j];

    if (node < N) {
        int beg = node ? rs[node - 1] : 0;
        int end = rs[node];
        const unsigned short* su = reinterpret_cast<const unsigned short*>(sup) + g * VPT;
        for (int j0 = beg; j0 < end; j0 += EB) {
            unsigned p[NE];
#pragma unroll
            for (int k = 0; k < NE; ++k) {
                int jl = j0 + k * GA + g;
                p[k] = edges[jl < end ? jl : end - 1];
            }
            int cnt = min(EB, end - j0);
            uint4 gv[EB];
            float wv[EB];
#pragma unroll
            for (int jj = 0; jj < EB; ++jj) {
                unsigned pe = __shfl(p[jj / GA], jj % GA, GA);
                wv[jj] = (float)(pe >> 17) * (1.0f / 32768.f);
                unsigned col = pe & 0x1FFFFu;
                if (jj < cnt)
                    gv[jj] = *reinterpret_cast<const uint4*>(su + (size_t)col * MA);
            }
#pragma unroll
            for (int jj = 0; jj < EB; ++jj) {
                if (jj >= cnt) break;
                float w = wv[jj];
                acc[0] += w * bflo(gv[jj].x); acc[1] += w * bfhi(gv[jj].x);
                acc[2] += w * bflo(gv[jj].y); acc[3] += w * bfhi(gv[jj].y);
                acc[4] += w * bflo(gv[jj].z); acc[5] += w * bfhi(gv[jj].z);
                acc[6] += w * bflo(gv[jj].w); acc[7] += w * bfhi(gv[jj].w);
            }
        }
    }
#pragma unroll
    for (int j = 0; j < VPT; ++j) acc[j] = lrelu(acc[j]);
    uint4 pk = { packbf(acc[0], acc[1]), packbf(acc[2], acc[3]),
                 packbf(acc[4], acc[5]), packbf(acc[6], acc[7]) };
    *reinterpret_cast<uint4*>(&atile[lr][g * 8]) = pk;
    __syncthreads();

    // ---- gemm phase: outS[tile rows] = atile @ W ----
    const int lane = tid & 63;
    const int wave = tid >> 6;
    const int tile = wave / CTB;
    const int ct = wave % CTB;
    const int lrow = lane & 15;
    const int lgrp = lane >> 4;

    bf16x8 bfrag[KH];
#pragma unroll
    for (int kh = 0; kh < KH; ++kh)
#pragma unroll
        for (int j = 0; j < 8; ++j)
            bfrag[kh][j] = (short)f2bf(WsF[(kh * 32 + lgrp * 8 + j) * MB + ct * 16 + lrow]);

    int nb = blockIdx.x * NPB + tile * 16;
    if (nb >= N) return;                      // N % 16 == 0: full tiles only
    bf16x8 afrag[KH];
#pragma unroll
    for (int kh = 0; kh < KH; ++kh)
        afrag[kh] = *reinterpret_cast<const bf16x8*>(&atile[tile * 16 + lrow][kh * 32 + lgrp * 8]);

    f32x4 a = {0.f, 0.f, 0.f, 0.f};
#pragma unroll
    for (int kh = 0; kh < KH; ++kh)
        a = __builtin_amdgcn_mfma_f32_16x16x32_bf16(afrag[kh], bfrag[kh], a, 0, 0, 0);

    unsigned short* outs = (unsigned short*)outS;
#pragma unroll
    for (int r = 0; r < 4; ++r) {
        int orow = nb + lgrp * 4 + r;
        outs[(size_t)orow * MB + ct * 16 + lrow] = f2bf(a[r]);
    }
}

// ---------------- final CSR aggregation (layer 3): unchanged from R12 ----------------

template <int M, int G, bool ACTOUT>
__global__ void __launch_bounds__(256)
agg_kernel(const int* __restrict__ rs, const unsigned* __restrict__ edges,
           const __hip_bfloat16* __restrict__ sup, const float* __restrict__ b,
           float* __restrict__ out, int N) {
    constexpr int VPT = M / G;       // 4
    constexpr int EB = 8;
    constexpr int NE = EB / G;
    int tid = blockIdx.x * blockDim.x + threadIdx.x;
    int node = tid / G;
    if (node >= N) return;
    int g = tid - node * G;

    float acc[VPT];
#pragma unroll
    for (int j = 0; j < VPT; ++j) acc[j] = b[g * VPT + j];

    int beg = node ? rs[node - 1] : 0;
    int end = rs[node];
    const unsigned short* su = reinterpret_cast<const unsigned short*>(sup) + g * VPT;

    for (int j0 = beg; j0 < end; j0 += EB) {
        unsigned p[NE];
#pragma unroll
        for (int k = 0; k < NE; ++k) {
            int jl = j0 + k * G + g;
            p[k] = edges[jl < end ? jl : end - 1];
        }
        int cnt = min(EB, end - j0);
        uint2 gv[EB];
        float wv[EB];
#pragma unroll
        for (int jj = 0; jj < EB; ++jj) {
            unsigned pe = __shfl(p[jj / G], jj % G, G);
            wv[jj] = (float)(pe >> 17) * (1.0f / 32768.f);
            unsigned col = pe & 0x1FFFFu;
            if (jj < cnt)
                gv[jj] = *reinterpret_cast<const uint2*>(su + (size_t)col * M);
        }
#pragma unroll
        for (int jj = 0; jj < EB; ++jj) {
            if (jj >= cnt) break;
            float w = wv[jj];
            acc[0] += w * bflo(gv[jj].x); acc[1] += w * bfhi(gv[jj].x);
            acc[2] += w * bflo(gv[jj].y); acc[3] += w * bfhi(gv[jj].y);
        }
    }
    if (ACTOUT) {
#pragma unroll
        for (int j = 0; j < VPT; ++j) acc[j] = lrelu(acc[j]);
    }
    float4 o = {acc[0], acc[1], acc[2], acc[3]};
    *reinterpret_cast<float4*>(out + (size_t)node * M + g * 4) = o;
}

extern "C" void kernel_launch(void* const* d_in, const int* in_sizes, int n_in,
                              void* d_out, int out_size, void* d_ws, size_t ws_size,
                              hipStream_t stream) {
    const float* x    = (const float*)d_in[0];
    const int*   erow = (const int*)  d_in[1];
    const int*   ecol = (const int*)  d_in[2];
    const float* ew   = (const float*)d_in[3];
    const float* W1   = (const float*)d_in[4];
    const float* b1   = (const float*)d_in[5];
    const float* W2   = (const float*)d_in[6];
    const float* b2   = (const float*)d_in[7];
    const float* W3   = (const float*)d_in[8];
    const float* b3   = (const float*)d_in[9];
    float* out = (float*)d_out;

    const int N = in_sizes[0] / 64;   // 100000
    const int E = in_sizes[1];        // 1000000

    auto cdiv = [](long a, long b) { return (int)((a + b - 1) / b); };
    const int NB   = cdiv(E, CHUNK);          // 245 edge chunks
    const int nbkt = cdiv(N, BKTSZ);          // 782 buckets
    const long T   = (long)nbkt * NB;         // 191,590 flat hist entries
    const int nsc  = cdiv(T, SCAN_CHUNK);     // 94 scan chunks (<= MAXNSC)

    // Workspace:
    //   [0,      12.8MB)  s1 (N*64 bf16)
    //   [12.8,   19.2MB)  s2 (N*32 bf16)
    //   [19.2,   22.4MB)  s3 (N*16 bf16)
    //   [22.4MB, ...)     I[T] (0.8MB), bsum[128], rs[N] (0.4MB),
    //                     eb1[E] int2 (8MB), edges[E] uint (4MB)
    char* wsc = (char*)d_ws;
    const size_t SZ64B = (size_t)N * 64 * 2;   // 12.8 MB
    const size_t SZ32B = (size_t)N * 32 * 2;   // 6.4 MB
    const size_t SZ16B = (size_t)N * 16 * 2;   // 3.2 MB
    __hip_bfloat16* s1 = (__hip_bfloat16*)(wsc);
    __hip_bfloat16* s2 = (__hip_bfloat16*)(wsc + SZ64B);
    __hip_bfloat16* s3 = (__hip_bfloat16*)(wsc + SZ64B + SZ32B);

    char* csr = wsc + SZ64B + SZ32B + SZ16B;
    int*      I     = (int*)csr;                   // T ints
    int*      bsum  = I + T;                       // MAXNSC ints
    int*      rs    = bsum + MAXNSC;               // N ints
    int2*     eb1   = (int2*)(rs + N);             // E int2
    unsigned* edges = (unsigned*)(eb1 + E);        // E uint (4B packed)

    const int B = 256;
    const int GB = cdiv(N, 128);                   // gemm1 blocks (NT=2, 128 nodes/blk)

    // ---- CSR build (hist overlapped with gemm1) ----
    fused_hist_gemm1_kernel<<<NB + GB, B, 0, stream>>>(erow, I, E, nbkt, NB, x, W1, s1, N);
    scan1_kernel<<<nsc, SCAN_T, 0, stream>>>(I, bsum, (int)T);
    place1_kernel<<<NB, B, 0, stream>>>(erow, ecol, ew, I, bsum, nsc, eb1, E, nbkt, NB);
    place2_kernel<<<nbkt, B, 0, stream>>>(eb1, I, bsum, nsc, edges, rs, N, NB);

    // ---- agg1 + gemm2 fused: s1 --agg--> LDS --@W2--> s2 ----
    fused_agg_gemm_kernel<64, 8, 32><<<cdiv(N, 32), B, 0, stream>>>(
        rs, edges, s1, b1, W2, s2, N);

    // ---- agg2 + gemm3 fused: s2 --agg--> LDS --@W3--> s3 ----
    fused_agg_gemm_kernel<32, 4, 16><<<cdiv(N, 64), B, 0, stream>>>(
        rs, edges, s2, b2, W3, s3, N);

    // ---- agg3: final aggregation + lrelu -> f32 out ----
    agg_kernel<16, 4, true><<<cdiv((long)N * 4, B), B, 0, stream>>>(rs, edges, s3, b3, out, N);
}

// Round 14
// 94.348 us; speedup vs baseline: 1.7098x; 1.0168x over previous
//
#include <hip/hip_runtime.h>
#include <hip/hip_bf16.h>

// 3-layer GCN, N=100000, E=1000000, dims 64 -> 64 -> 32 -> 16.
// CSR via two-level LDS bucket counting sort (zero global atomics).
// R14: (a) gemm1 fusion moved from hist -> place1 (longest independent CSR
// stage; R13 chain had hist+scan serial ahead of place1). (b) place2 stages
// its bucket's edges in LDS once (guarded <=2048) -> one global read of eb1
// instead of two. fag1/fag2/agg3 byte-identical to R13.

typedef short bf16x8 __attribute__((ext_vector_type(8)));
typedef float f32x4 __attribute__((ext_vector_type(4)));

__device__ __forceinline__ float lrelu(float v) { return v > 0.0f ? v : 0.25f * v; }
__device__ __forceinline__ float bflo(unsigned u) { return __uint_as_float(u << 16); }
__device__ __forceinline__ float bfhi(unsigned u) { return __uint_as_float(u & 0xffff0000u); }
__device__ __forceinline__ unsigned short f2bf(float f) {          // round-to-nearest-even
    unsigned u = __float_as_uint(f);
    return (unsigned short)((u + 0x7fffu + ((u >> 16) & 1u)) >> 16);
}
__device__ __forceinline__ unsigned packbf(float a, float b) {
    return (unsigned)f2bf(a) | ((unsigned)f2bf(b) << 16);
}

// ---------------- bucket counting-sort CSR build ----------------

constexpr int SCAN_T = 256;
constexpr int SCAN_PER = 8;
constexpr int SCAN_CHUNK = SCAN_T * SCAN_PER;  // 2048 (scan1 granularity; getI >>11)
constexpr int CHUNK = 4096;                    // edges per hist/place1 block
constexpr int BKT_BITS = 7;
constexpr int BKTSZ = 128;                     // nodes per bucket
constexpr int MAXBKT = 1024;                   // LDS bins (N <= 131072)
constexpr int MAXNSC = 128;                    // max scan1 chunks (T <= 262144)
constexpr int P2CAP = 2048;                    // place2 LDS edge cap (avg 1280/bucket)

__device__ __forceinline__ void build_bofs(const int* __restrict__ bsum, int nsc,
                                           int* tmp, int* bofs) {
    int t = threadIdx.x;
    int v = (t < MAXNSC && t < nsc) ? bsum[t] : 0;
    if (t < MAXNSC) tmp[t] = v;
    __syncthreads();
    for (int off = 1; off < MAXNSC; off <<= 1) {
        int add = (t < MAXNSC && t >= off) ? tmp[t - off] : 0;
        __syncthreads();
        if (t < MAXNSC) tmp[t] += add;
        __syncthreads();
    }
    if (t < MAXNSC) bofs[t] = tmp[t] - v;   // exclusive
    __syncthreads();
}

__device__ __forceinline__ int getI(const int* __restrict__ I,
                                    const int* __restrict__ bofs, size_t idx) {
    return I[idx] + bofs[idx >> 11];    // 2048-element scan chunks
}

__global__ void __launch_bounds__(256)
hist1_kernel(const int* __restrict__ row, int* __restrict__ hists,
             int E, int nbkt, int NB) {
    __shared__ int hist[MAXBKT];
    for (int i = threadIdx.x; i < nbkt; i += 256) hist[i] = 0;
    __syncthreads();
    int e0 = blockIdx.x * CHUNK;
    int e1 = min(e0 + CHUNK, E);
    for (int e = e0 + threadIdx.x; e < e1; e += 256)
        atomicAdd(&hist[row[e] >> BKT_BITS], 1);            // LDS atomic
    __syncthreads();
    for (int i = threadIdx.x; i < nbkt; i += 256)
        hists[(size_t)i * NB + blockIdx.x] = hist[i];
}

__global__ void __launch_bounds__(SCAN_T)
scan1_kernel(int* __restrict__ I, int* __restrict__ bsum, int T) {
    __shared__ int lds[SCAN_T];
    int t = threadIdx.x;
    int base = blockIdx.x * SCAN_CHUNK + t * SCAN_PER;
    int v[SCAN_PER];
    int run = 0;
#pragma unroll
    for (int j = 0; j < SCAN_PER; ++j) {
        int i = base + j;
        run += (i < T) ? I[i] : 0;
        v[j] = run;
    }
    lds[t] = run;
    __syncthreads();
    for (int off = 1; off < SCAN_T; off <<= 1) {
        int add = (t >= off) ? lds[t - off] : 0;
        __syncthreads();
        lds[t] += add;
        __syncthreads();
    }
    int excl = lds[t] - run;
#pragma unroll
    for (int j = 0; j < SCAN_PER; ++j) {
        int i = base + j;
        if (i < T) I[i] = v[j] + excl;
    }
    if (t == SCAN_T - 1) bsum[blockIdx.x] = lds[t];
}

// ---------------- fused: place1 (blocks [0,NB)) + MFMA gemm1 (blocks [NB,..)) ----
// Shared LDS arena: place1 uses srow[4096]+hist[1024]+tmp[128]+bofs[128] ints
// (21.5KB); gemm1 uses 16KB floats for W1.

__global__ void __launch_bounds__(256)
fused_place1_gemm1_kernel(const int* __restrict__ row, const int* __restrict__ col,
                          const float* __restrict__ w, const int* __restrict__ I,
                          const int* __restrict__ bsum, int nsc, int2* __restrict__ eb1,
                          int E, int nbkt, int NB,
                          const float* __restrict__ x, const float* __restrict__ W1,
                          __hip_bfloat16* __restrict__ s1, int N) {
    __shared__ int arena[CHUNK + MAXBKT + 2 * MAXNSC];   // 21.5 KB
    if ((int)blockIdx.x < NB) {
        // ---- place1 role ----
        int* srow = arena;
        int* hist = arena + CHUNK;
        int* tmp  = arena + CHUNK + MAXBKT;
        int* bofs = tmp + MAXNSC;
        build_bofs(bsum, nsc, tmp, bofs);
        for (int i = threadIdx.x; i < nbkt; i += 256) hist[i] = 0;
        int e0 = blockIdx.x * CHUNK;
        int e1 = min(e0 + CHUNK, E);
        for (int e = e0 + threadIdx.x; e < e1; e += 256) srow[e - e0] = row[e];
        __syncthreads();
        for (int i = threadIdx.x; i < e1 - e0; i += 256)
            atomicAdd(&hist[srow[i] >> BKT_BITS], 1);
        __syncthreads();
        for (int i = threadIdx.x; i < nbkt; i += 256) {
            size_t idx = (size_t)i * NB + blockIdx.x;
            hist[i] = getI(I, bofs, idx) - hist[i];
        }
        __syncthreads();
        for (int e = e0 + threadIdx.x; e < e1; e += 256) {
            int r = srow[e - e0];
            int pos = atomicAdd(&hist[r >> BKT_BITS], 1);    // LDS atomic, returns slot
            eb1[pos] = make_int2(((r & (BKTSZ - 1)) << 20) | col[e], __float_as_int(w[e]));
        }
        return;
    }
    // ---- MFMA gemm1 role: s1 = bf16(x) @ W1, K=64, M=64, NT=2 ----
    constexpr int K = 64, M = 64, NT = 2, CT = M / 16, KH = K / 32;
    float* Ws = reinterpret_cast<float*>(arena);
    for (int i = threadIdx.x; i < K * M / 4; i += 256)
        reinterpret_cast<float4*>(Ws)[i] = reinterpret_cast<const float4*>(W1)[i];
    __syncthreads();
    const int lane = threadIdx.x & 63;
    const int wave = threadIdx.x >> 6;
    const int lrow = lane & 15;
    const int lgrp = lane >> 4;

    bf16x8 bfrag[CT][KH];
#pragma unroll
    for (int ct = 0; ct < CT; ++ct)
#pragma unroll
        for (int kh = 0; kh < KH; ++kh)
#pragma unroll
            for (int j = 0; j < 8; ++j)
                bfrag[ct][kh][j] =
                    (short)f2bf(Ws[(kh * 32 + lgrp * 8 + j) * M + ct * 16 + lrow]);

    unsigned short* outs = (unsigned short*)s1;
    const int wave_base = ((int)blockIdx.x - NB) * (4 * NT * 16) + wave * (NT * 16);
#pragma unroll
    for (int t = 0; t < NT; ++t) {
        int nb = wave_base + t * 16;
        if (nb >= N) break;
        int arow = nb + lrow;
        bf16x8 afrag[KH];
#pragma unroll
        for (int kh = 0; kh < KH; ++kh) {
            const float* ap = x + (size_t)arow * K + kh * 32 + lgrp * 8;
            float4 u0 = *reinterpret_cast<const float4*>(ap);
            float4 u1 = *reinterpret_cast<const float4*>(ap + 4);
            afrag[kh][0] = (short)f2bf(u0.x); afrag[kh][1] = (short)f2bf(u0.y);
            afrag[kh][2] = (short)f2bf(u0.z); afrag[kh][3] = (short)f2bf(u0.w);
            afrag[kh][4] = (short)f2bf(u1.x); afrag[kh][5] = (short)f2bf(u1.y);
            afrag[kh][6] = (short)f2bf(u1.z); afrag[kh][7] = (short)f2bf(u1.w);
        }
        f32x4 acc[CT];
#pragma unroll
        for (int ct = 0; ct < CT; ++ct) { acc[ct][0]=0.f; acc[ct][1]=0.f; acc[ct][2]=0.f; acc[ct][3]=0.f; }
#pragma unroll
        for (int ct = 0; ct < CT; ++ct)
#pragma unroll
            for (int kh = 0; kh < KH; ++kh)
                acc[ct] = __builtin_amdgcn_mfma_f32_16x16x32_bf16(
                    afrag[kh], bfrag[ct][kh], acc[ct], 0, 0, 0);
#pragma unroll
        for (int ct = 0; ct < CT; ++ct)
#pragma unroll
            for (int r = 0; r < 4; ++r) {
                int orow = nb + lgrp * 4 + r;
                outs[(size_t)orow * M + ct * 16 + lrow] = f2bf(acc[ct][r]);
            }
    }
}

// one block per bucket: LDS-staged single-pass per-node CSR; emits packed edges[] + rs[].
__global__ void __launch_bounds__(256)
place2_kernel(const int2* __restrict__ eb1, const int* __restrict__ I,
              const int* __restrict__ bsum, int nsc, unsigned* __restrict__ edges,
              int* __restrict__ rs, int N, int NB) {
    __shared__ int2 se[P2CAP];        // 16 KB staged edges
    __shared__ int hist[BKTSZ];
    __shared__ int scanv[BKTSZ];
    __shared__ int tmp[MAXNSC];
    __shared__ int bofs[MAXNSC];
    build_bofs(bsum, nsc, tmp, bofs);
    int b = blockIdx.x;
    int t = threadIdx.x;
    int bstart = (b == 0) ? 0 : getI(I, bofs, (size_t)b * NB - 1);
    int bend   = getI(I, bofs, (size_t)(b + 1) * NB - 1);
    int cnt = bend - bstart;
    bool inlds = (cnt <= P2CAP);
    if (inlds)
        for (int e = t; e < cnt; e += 256) se[e] = eb1[bstart + e];   // one coalesced read
    if (t < BKTSZ) hist[t] = 0;
    __syncthreads();
    for (int e = t; e < cnt; e += 256) {
        int ex = inlds ? se[e].x : eb1[bstart + e].x;
        atomicAdd(&hist[(ex >> 20) & (BKTSZ - 1)], 1);
    }
    __syncthreads();
    int cval = (t < BKTSZ) ? hist[t] : 0;
    if (t < BKTSZ) scanv[t] = cval;
    __syncthreads();
    for (int off = 1; off < BKTSZ; off <<= 1) {
        int add = (t < BKTSZ && t >= off) ? scanv[t - off] : 0;
        __syncthreads();
        if (t < BKTSZ) scanv[t] += add;
        __syncthreads();
    }
    if (t < BKTSZ) {
        int gnode = b * BKTSZ + t;
        if (gnode < N) rs[gnode] = bstart + scanv[t];        // inclusive ends
        hist[t] = bstart + scanv[t] - cval;                  // node base for placing
    }
    __syncthreads();
    for (int e = t; e < cnt; e += 256) {
        int2 ev = inlds ? se[e] : eb1[bstart + e];
        int lrow = (ev.x >> 20) & (BKTSZ - 1);
        float w = __int_as_float(ev.y);
        unsigned q = (unsigned)(w * 32768.f + 0.5f);
        q = q > 32767u ? 32767u : q;
        unsigned packed = (q << 17) | (unsigned)(ev.x & 0x1FFFF);   // w15 | col17
        int pos = atomicAdd(&hist[lrow], 1);                 // LDS atomic
        edges[pos] = packed;
    }
}

// ---------------- fused agg_k + gemm_{k+1} (unchanged from R13) ----------------

template <int MA, int GA, int MB>
__global__ void __launch_bounds__(256)
fused_agg_gemm_kernel(const int* __restrict__ rs, const unsigned* __restrict__ edges,
                      const __hip_bfloat16* __restrict__ sup, const float* __restrict__ bias,
                      const float* __restrict__ W, __hip_bfloat16* __restrict__ outS, int N) {
    constexpr int VPT = MA / GA;      // = 8
    static_assert(VPT == 8, "agg phase assumes 8 bf16 per lane");
    constexpr int NPB = 256 / GA;     // nodes per block (32 or 64)
    constexpr int KH = MA / 32, CTB = MB / 16, TILES = NPB / 16;
    static_assert(TILES * CTB == 4, "4 waves must cover (tile,ct) space");
    constexpr int STR = MA + 8;       // LDS row stride in bf16
    constexpr int EB = 8, NE = EB / GA;

    __shared__ float WsF[MA * MB];
    __shared__ unsigned short atile[NPB][STR];

    for (int i = threadIdx.x; i < MA * MB / 4; i += 256)
        reinterpret_cast<float4*>(WsF)[i] = reinterpret_cast<const float4*>(W)[i];

    int tid = threadIdx.x;
    int lr = tid / GA;
    int g = tid & (GA - 1);
    int node = blockIdx.x * NPB + lr;

    float acc[VPT];
#pragma unroll
    for (int j = 0; j < VPT; ++j) acc[j] = bias[g * VPT + j];

    if (node < N) {
        int beg = node ? rs[node - 1] : 0;
        int end = rs[node];
        const unsigned short* su = reinterpret_cast<const unsigned short*>(sup) + g * VPT;
        for (int j0 = beg; j0 < end; j0 += EB) {
            unsigned p[NE];
#pragma unroll
            for (int k = 0; k < NE; ++k) {
                int jl = j0 + k * GA + g;
                p[k] = edges[jl < end ? jl : end - 1];
            }
            int cnt = min(EB, end - j0);
            uint4 gv[EB];
            float wv[EB];
#pragma unroll
            for (int jj = 0; jj < EB; ++jj) {
                unsigned pe = __shfl(p[jj / GA], jj % GA, GA);
                wv[jj] = (float)(pe >> 17) * (1.0f / 32768.f);
                unsigned col = pe & 0x1FFFFu;
                if (jj < cnt)
                    gv[jj] = *reinterpret_cast<const uint4*>(su + (size_t)col * MA);
            }
#pragma unroll
            for (int jj = 0; jj < EB; ++jj) {
                if (jj >= cnt) break;
                float w = wv[jj];
                acc[0] += w * bflo(gv[jj].x); acc[1] += w * bfhi(gv[jj].x);
                acc[2] += w * bflo(gv[jj].y); acc[3] += w * bfhi(gv[jj].y);
                acc[4] += w * bflo(gv[jj].z); acc[5] += w * bfhi(gv[jj].z);
                acc[6] += w * bflo(gv[jj].w); acc[7] += w * bfhi(gv[jj].w);
            }
        }
    }
#pragma unroll
    for (int j = 0; j < VPT; ++j) acc[j] = lrelu(acc[j]);
    uint4 pk = { packbf(acc[0], acc[1]), packbf(acc[2], acc[3]),
                 packbf(acc[4], acc[5]), packbf(acc[6], acc[7]) };
    *reinterpret_cast<uint4*>(&atile[lr][g * 8]) = pk;
    __syncthreads();

    const int lane = tid & 63;
    const int wave = tid >> 6;
    const int tile = wave / CTB;
    const int ct = wave % CTB;
    const int lrow = lane & 15;
    const int lgrp = lane >> 4;

    bf16x8 bfrag[KH];
#pragma unroll
    for (int kh = 0; kh < KH; ++kh)
#pragma unroll
        for (int j = 0; j < 8; ++j)
            bfrag[kh][j] = (short)f2bf(WsF[(kh * 32 + lgrp * 8 + j) * MB + ct * 16 + lrow]);

    int nb = blockIdx.x * NPB + tile * 16;
    if (nb >= N) return;
    bf16x8 afrag[KH];
#pragma unroll
    for (int kh = 0; kh < KH; ++kh)
        afrag[kh] = *reinterpret_cast<const bf16x8*>(&atile[tile * 16 + lrow][kh * 32 + lgrp * 8]);

    f32x4 a = {0.f, 0.f, 0.f, 0.f};
#pragma unroll
    for (int kh = 0; kh < KH; ++kh)
        a = __builtin_amdgcn_mfma_f32_16x16x32_bf16(afrag[kh], bfrag[kh], a, 0, 0, 0);

    unsigned short* outs = (unsigned short*)outS;
#pragma unroll
    for (int r = 0; r < 4; ++r) {
        int orow = nb + lgrp * 4 + r;
        outs[(size_t)orow * MB + ct * 16 + lrow] = f2bf(a[r]);
    }
}

// ---------------- final CSR aggregation (layer 3, unchanged) ----------------

template <int M, int G, bool ACTOUT>
__global__ void __launch_bounds__(256)
agg_kernel(const int* __restrict__ rs, const unsigned* __restrict__ edges,
           const __hip_bfloat16* __restrict__ sup, const float* __restrict__ b,
           float* __restrict__ out, int N) {
    constexpr int VPT = M / G;       // 4
    constexpr int EB = 8;
    constexpr int NE = EB / G;
    int tid = blockIdx.x * blockDim.x + threadIdx.x;
    int node = tid / G;
    if (node >= N) return;
    int g = tid - node * G;

    float acc[VPT];
#pragma unroll
    for (int j = 0; j < VPT; ++j) acc[j] = b[g * VPT + j];

    int beg = node ? rs[node - 1] : 0;
    int end = rs[node];
    const unsigned short* su = reinterpret_cast<const unsigned short*>(sup) + g * VPT;

    for (int j0 = beg; j0 < end; j0 += EB) {
        unsigned p[NE];
#pragma unroll
        for (int k = 0; k < NE; ++k) {
            int jl = j0 + k * G + g;
            p[k] = edges[jl < end ? jl : end - 1];
        }
        int cnt = min(EB, end - j0);
        uint2 gv[EB];
        float wv[EB];
#pragma unroll
        for (int jj = 0; jj < EB; ++jj) {
            unsigned pe = __shfl(p[jj / G], jj % G, G);
            wv[jj] = (float)(pe >> 17) * (1.0f / 32768.f);
            unsigned col = pe & 0x1FFFFu;
            if (jj < cnt)
                gv[jj] = *reinterpret_cast<const uint2*>(su + (size_t)col * M);
        }
#pragma unroll
        for (int jj = 0; jj < EB; ++jj) {
            if (jj >= cnt) break;
            float w = wv[jj];
            acc[0] += w * bflo(gv[jj].x); acc[1] += w * bfhi(gv[jj].x);
            acc[2] += w * bflo(gv[jj].y); acc[3] += w * bfhi(gv[jj].y);
        }
    }
    if (ACTOUT) {
#pragma unroll
        for (int j = 0; j < VPT; ++j) acc[j] = lrelu(acc[j]);
    }
    float4 o = {acc[0], acc[1], acc[2], acc[3]};
    *reinterpret_cast<float4*>(out + (size_t)node * M + g * 4) = o;
}

extern "C" void kernel_launch(void* const* d_in, const int* in_sizes, int n_in,
                              void* d_out, int out_size, void* d_ws, size_t ws_size,
                              hipStream_t stream) {
    const float* x    = (const float*)d_in[0];
    const int*   erow = (const int*)  d_in[1];
    const int*   ecol = (const int*)  d_in[2];
    const float* ew   = (const float*)d_in[3];
    const float* W1   = (const float*)d_in[4];
    const float* b1   = (const float*)d_in[5];
    const float* W2   = (const float*)d_in[6];
    const float* b2   = (const float*)d_in[7];
    const float* W3   = (const float*)d_in[8];
    const float* b3   = (const float*)d_in[9];
    float* out = (float*)d_out;

    const int N = in_sizes[0] / 64;   // 100000
    const int E = in_sizes[1];        // 1000000

    auto cdiv = [](long a, long b) { return (int)((a + b - 1) / b); };
    const int NB   = cdiv(E, CHUNK);          // 245 edge chunks
    const int nbkt = cdiv(N, BKTSZ);          // 782 buckets
    const long T   = (long)nbkt * NB;         // 191,590 flat hist entries
    const int nsc  = cdiv(T, SCAN_CHUNK);     // 94 scan chunks (<= MAXNSC)

    // Workspace:
    //   [0,      12.8MB)  s1 (N*64 bf16)
    //   [12.8,   19.2MB)  s2 (N*32 bf16)
    //   [19.2,   22.4MB)  s3 (N*16 bf16)
    //   [22.4MB, ...)     I[T] (0.8MB), bsum[128], rs[N] (0.4MB),
    //                     eb1[E] int2 (8MB), edges[E] uint (4MB)
    char* wsc = (char*)d_ws;
    const size_t SZ64B = (size_t)N * 64 * 2;   // 12.8 MB
    const size_t SZ32B = (size_t)N * 32 * 2;   // 6.4 MB
    const size_t SZ16B = (size_t)N * 16 * 2;   // 3.2 MB
    __hip_bfloat16* s1 = (__hip_bfloat16*)(wsc);
    __hip_bfloat16* s2 = (__hip_bfloat16*)(wsc + SZ64B);
    __hip_bfloat16* s3 = (__hip_bfloat16*)(wsc + SZ64B + SZ32B);

    char* csr = wsc + SZ64B + SZ32B + SZ16B;
    int*      I     = (int*)csr;                   // T ints
    int*      bsum  = I + T;                       // MAXNSC ints
    int*      rs    = bsum + MAXNSC;               // N ints
    int2*     eb1   = (int2*)(rs + N);             // E int2
    unsigned* edges = (unsigned*)(eb1 + E);        // E uint (4B packed)

    const int B = 256;
    const int GB = cdiv(N, 128);                   // gemm1 blocks (NT=2, 128 nodes/blk)

    // ---- CSR build; gemm1 overlapped with place1 ----
    hist1_kernel<<<NB, B, 0, stream>>>(erow, I, E, nbkt, NB);
    scan1_kernel<<<nsc, SCAN_T, 0, stream>>>(I, bsum, (int)T);
    fused_place1_gemm1_kernel<<<NB + GB, B, 0, stream>>>(
        erow, ecol, ew, I, bsum, nsc, eb1, E, nbkt, NB, x, W1, s1, N);
    place2_kernel<<<nbkt, B, 0, stream>>>(eb1, I, bsum, nsc, edges, rs, N, NB);

    // ---- agg1 + gemm2 fused: s1 --agg--> LDS --@W2--> s2 ----
    fused_agg_gemm_kernel<64, 8, 32><<<cdiv(N, 32), B, 0, stream>>>(
        rs, edges, s1, b1, W2, s2, N);

    // ---- agg2 + gemm3 fused: s2 --agg--> LDS --@W3--> s3 ----
    fused_agg_gemm_kernel<32, 4, 16><<<cdiv(N, 64), B, 0, stream>>>(
        rs, edges, s2, b2, W3, s3, N);

    // ---- agg3: final aggregation + lrelu -> f32 out ----
    agg_kernel<16, 4, true><<<cdiv((long)N * 4, B), B, 0, stream>>>(rs, edges, s3, b3, out, N);
}